// Round 15
// baseline (425.779 us; speedup 1.0000x reference)
//
#include <hip/hip_runtime.h>
#include <hip/hip_fp16.h>
#include <math.h>

#define NN 50000
#define EE 800000
#define HH 64
#define NBASIS 8
#define NLAYER 2
#define NGRAPH 64
#define NBLK1 49  // ceil(NN/1024)

using half2_t = decltype(__builtin_amdgcn_cvt_pkrtz(0.0f, 0.0f));
typedef _Float16 f16x8 __attribute__((ext_vector_type(8)));
typedef float f32x4 __attribute__((ext_vector_type(4)));

union U4H8 { uint4 u; f16x8 h; };

__device__ __forceinline__ float silu_f(float v) {
    return v * (1.0f / (1.0f + __expf(-v)));
}

__device__ __forceinline__ unsigned pk2(float a, float b) {
    union { half2_t h; unsigned u; } x;
    x.h = __builtin_amdgcn_cvt_pkrtz(a, b);
    return x.u;
}

__device__ __forceinline__ half2_t u2h(unsigned u) {
    union { unsigned u; half2_t h; } x; x.u = u; return x.h;
}

// fused prep: embed gather (blocks 0..6249), weight prepack (6250..6361),
// degree count (6362..9486). x is f16-only (xh) — no fp32 copy.
__global__ __launch_bounds__(256) void prep_k(
    const int* __restrict__ z, const float* __restrict__ embed,
    unsigned* __restrict__ xh,
    const float* __restrict__ msg_w1, const float* __restrict__ msg_w2,
    const float* __restrict__ upd_w1, const float* __restrict__ upd_w2,
    const float* __restrict__ eh_w1,
    unsigned* __restrict__ w1t, unsigned* __restrict__ w2t,
    unsigned* __restrict__ w1tu, unsigned* __restrict__ w2tu,
    unsigned* __restrict__ ehw1t,
    const int* __restrict__ ecol, int* __restrict__ deg)
{
    int b = blockIdx.x;
    if (b < 6250) {                       // embed gather: NN*32 pairs
        int idx = b * 256 + threadIdx.x;  // < 1,600,000 always
        int n = idx >> 5;
        int p = idx & 31;
        const float2* er = (const float2*)(embed + ((size_t)z[n] << 6));
        float2 v = er[p];
        xh[idx] = pk2(v.x, v.y);
    } else if (b < 6362) {                // weight prepack, 28672 threads
        int idx = (b - 6250) * 256 + threadIdx.x;
        if (idx < 10240) {                    // msg w1t [l][f 64][kp 80]
            int l = idx / 5120, rem = idx % 5120;
            int f = rem / 80, kp = rem % 80;
            const float* w = msg_w1 + (size_t)l * 136 * 64;
            unsigned v = 0;
            if (kp < 68) v = pk2(w[(2*kp)*64 + f], w[(2*kp+1)*64 + f]);
            w1t[idx] = v;
        } else if (idx < 14336) {             // msg w2t [l][n 64][kp 32]
            int j = idx - 10240;
            int l = j / 2048, rem = j % 2048;
            int n = rem / 32, kp = rem % 32;
            const float* w = msg_w2 + (size_t)l * 64 * 64;
            w2t[j] = pk2(w[(2*kp)*64 + n], w[(2*kp+1)*64 + n]);
        } else if (idx < 22528) {             // upd w1tu [l][f 64][kp 64]
            int j = idx - 14336;
            int l = j / 4096, rem = j % 4096;
            int f = rem >> 6, kp = rem & 63;
            const float* w = upd_w1 + (size_t)l * 128 * 64;
            w1tu[j] = pk2(w[(2*kp)*64 + f], w[(2*kp+1)*64 + f]);
        } else if (idx < 26624) {             // upd w2tu [l][n 64][kp 32]
            int j = idx - 22528;
            int l = j / 2048, rem = j % 2048;
            int n = rem / 32, kp = rem % 32;
            const float* w = upd_w2 + (size_t)l * 64 * 64;
            w2tu[j] = pk2(w[(2*kp)*64 + n], w[(2*kp+1)*64 + n]);
        } else if (idx < 28672) {             // head ehw1t [f 64][kp 32]
            int j = idx - 26624;
            int f = j / 32, kp = j % 32;
            ehw1t[j] = pk2(eh_w1[(2*kp)*64 + f], eh_w1[(2*kp+1)*64 + f]);
        }
    } else {                              // degree count
        int e = (b - 6362) * 256 + threadIdx.x;
        if (e < EE) atomicAdd(&deg[ecol[e]], 1);
    }
}

__global__ __launch_bounds__(1024) void scan1_k(
    const int* __restrict__ deg, int* __restrict__ cursor,
    int* __restrict__ bsum)
{
    __shared__ int wsum[16];
    int t = threadIdx.x, lane = t & 63, wave = t >> 6;
    int i = blockIdx.x * 1024 + t;
    int v = (i < NN) ? deg[i] : 0;
    int s = v;
#pragma unroll
    for (int off = 1; off < 64; off <<= 1) {
        int tv = __shfl_up(s, off, 64);
        if (lane >= off) s += tv;
    }
    if (lane == 63) wsum[wave] = s;
    __syncthreads();
    if (wave == 0) {
        int ws = (lane < 16) ? wsum[lane] : 0;
        int ss = ws;
#pragma unroll
        for (int off = 1; off < 16; off <<= 1) {
            int tv = __shfl_up(ss, off, 64);
            if (lane >= off) ss += tv;
        }
        if (lane < 16) wsum[lane] = ss - ws;
    }
    __syncthreads();
    int excl = wsum[wave] + s - v;
    if (i < NN) cursor[i] = excl;     // block-local exclusive scan
    if (t == 1023) bsum[blockIdx.x] = excl + v;
}

__global__ __launch_bounds__(64) void scan2_k(int* __restrict__ bsum)
{
    int lane = threadIdx.x;
    int v = (lane < NBLK1) ? bsum[lane] : 0;
    int s = v;
#pragma unroll
    for (int off = 1; off < 64; off <<= 1) {
        int tv = __shfl_up(s, off, 64);
        if (lane >= off) s += tv;
    }
    if (lane < NBLK1) bsum[lane] = s - v;
}

// scatter: one interleaved uint4 {row, col, d_bits, 0} per sorted slot
__global__ __launch_bounds__(256) void scatter_k(
    const int* __restrict__ erow, const int* __restrict__ ecol,
    const float* __restrict__ pos,
    int* __restrict__ cursor, const int* __restrict__ bsum,
    uint4* __restrict__ edgeS)
{
    int e = blockIdx.x * 256 + threadIdx.x;
    if (e >= EE) return;
    int c = ecol[e], r = erow[e];
    int slot = atomicAdd(&cursor[c], 1) + bsum[c >> 10];
    float dx = pos[3*r]   - pos[3*c];
    float dy = pos[3*r+1] - pos[3*c+1];
    float dz = pos[3*r+2] - pos[3*c+2];
    float d = sqrtf(dx*dx + dy*dy + dz*dz);
    uint4 v;
    v.x = (unsigned)r; v.y = (unsigned)c;
    v.z = __float_as_uint(d); v.w = 0;
    edgeS[slot] = v;
}

// MFMA msg kernel: 256-thread blocks = 4 private waves x 64 sorted edges.
// Barriers kept (r13: removing de-synced waves, +24%). (256,4): regs ~128
// (r11: tighter bound spills). agg is f16: interior runs use 2B plain
// stores, boundaries use pk f16 atomics (partner half = 0; safe because
// run boundaries are identical for both columns of a pair). Block index
// XCD-swizzled so each XCD gets a contiguous sorted-edge range.
__global__ __launch_bounds__(256, 4) void msg_k(
    const uint4* __restrict__ edgeS,
    const unsigned* __restrict__ xh,
    const unsigned* __restrict__ w1t, const float* __restrict__ b1,
    const unsigned* __restrict__ w2t, const float* __restrict__ b2,
    __half* __restrict__ agg)
{
    __shared__ __align__(16) unsigned earr[4][64 * 4];
    __shared__ int ckey_s[4][64];
    __shared__ int rkey_s[4][64];
    __shared__ float Mbuf[4][64 * 33];

    const int wid  = threadIdx.x >> 6;
    const int lane = threadIdx.x & 63;
    const int q = lane >> 4, n15 = lane & 15;

    // XCD swizzle: presume round-robin blockIdx%8 -> XCD; give each XCD a
    // contiguous range of sorted-edge blocks (L2 locality for xh + agg).
    const int NB = EE / 256;          // 3125
    const int bcnt = NB >> 3, brem = NB & 7;
    int xx = blockIdx.x & 7, ii = blockIdx.x >> 3;
    int bid = xx * bcnt + ((xx < brem) ? xx : brem) + ii;
    const size_t base = (size_t)bid * 256 + wid * 64;

    int mykey;
    // ---- per-edge prep (single coalesced 16B read) ----
    {
        uint4 ev = edgeS[base + lane];
        rkey_s[wid][lane] = (int)ev.x;
        mykey = (int)ev.y;
        ckey_s[wid][lane] = mykey;
        float d = __uint_as_float(ev.z);
        float env = 0.0f;
        if (d < 5.0f) {
            float cv = __cosf(d * 0.31415926535897932f);  // pi/(2*CUTOFF)
            env = cv * cv;
        }
        float scale = (d > 0.0f) ? (env / d) : env;
        float ea[NBASIS];
#pragma unroll
        for (int k = 0; k < NBASIS; ++k)
            ea[k] = __sinf((float)(k + 1) * 0.62831853071795865f * d) * scale;
#pragma unroll
        for (int p = 0; p < 4; ++p)
            earr[wid][lane * 4 + p] = pk2(ea[2*p], ea[2*p+1]);
    }
    // boundary bitmask: bit L set iff key[L] != key[L-1]
    int pkk = __shfl_up(mykey, 1, 64);
    unsigned long long bmask = __ballot(lane > 0 && mykey != pkk);
    unsigned m32 = (unsigned)(bmask >> (lane & 32));  // my strip's 32 bits
    __syncthreads();

    int cn[4], rn[4];
#pragma unroll
    for (int nt = 0; nt < 4; ++nt) {
        int eB = nt * 16 + n15;
        cn[nt] = ckey_s[wid][eB];
        rn[nt] = rkey_s[wid][eB];
    }

    // ---- GEMM1, frags streamed per ks ----
    f32x4 acc1[4][4];
#pragma unroll
    for (int mt = 0; mt < 4; ++mt) {
        f32x4 binit = *(const f32x4*)(b1 + mt * 16 + q * 4);
#pragma unroll
        for (int nt = 0; nt < 4; ++nt) acc1[mt][nt] = binit;
    }
#pragma unroll
    for (int ks = 0; ks < 5; ++ks) {
        U4H8 bfk[4];
#pragma unroll
        for (int nt = 0; nt < 4; ++nt) {
            if (ks == 4) {
                uint4 zz; zz.x = zz.y = zz.z = zz.w = 0;
                bfk[nt].u = (q == 0) ? *(const uint4*)(earr[wid] + (nt * 16 + n15) * 4) : zz;
            } else if (ks < 2) {
                bfk[nt].u = ((const uint4*)(xh + ((size_t)cn[nt] << 5)))[ks * 4 + q];
            } else {
                bfk[nt].u = ((const uint4*)(xh + ((size_t)rn[nt] << 5)))[(ks - 2) * 4 + q];
            }
        }
#pragma unroll
        for (int mt = 0; mt < 4; ++mt) {
            U4H8 af;
            af.u = *(const uint4*)(w1t + (size_t)(mt * 16 + n15) * 80 + ks * 16 + q * 4);
#pragma unroll
            for (int nt = 0; nt < 4; ++nt)
                acc1[mt][nt] = __builtin_amdgcn_mfma_f32_16x16x32_f16(
                    af.h, bfk[nt].h, acc1[mt][nt], 0, 0, 0);
        }
    }

    // ---- silu + pack ----
    unsigned psrc[4][4][2];
#pragma unroll
    for (int mt = 0; mt < 4; ++mt)
#pragma unroll
        for (int nt = 0; nt < 4; ++nt) {
            psrc[mt][nt][0] = pk2(silu_f(acc1[mt][nt][0]), silu_f(acc1[mt][nt][1]));
            psrc[mt][nt][1] = pk2(silu_f(acc1[mt][nt][2]), silu_f(acc1[mt][nt][3]));
        }

    // ---- GEMM2 ----
    f32x4 acc2[4][4];
#pragma unroll
    for (int nt = 0; nt < 4; ++nt) {
        float b2v = b2[nt * 16 + n15];
        f32x4 binit; binit[0] = b2v; binit[1] = b2v; binit[2] = b2v; binit[3] = b2v;
#pragma unroll
        for (int et = 0; et < 4; ++et) acc2[et][nt] = binit;
    }
#pragma unroll
    for (int ks2 = 0; ks2 < 2; ++ks2) {
        U4H8 wb[4];
#pragma unroll
        for (int nt = 0; nt < 4; ++nt)
            wb[nt].u = *(const uint4*)(w2t + (size_t)(nt * 16 + n15) * 32 + ks2 * 16 + q * 4);
#pragma unroll
        for (int et = 0; et < 4; ++et) {
            unsigned tmp[4];
#pragma unroll
            for (int jr = 0; jr < 4; ++jr) {
                int srcl = (2 * (q & 1) + (jr >> 1)) * 16 + n15;
                unsigned v0 = (unsigned)__shfl((int)psrc[2 * ks2][et][jr & 1], srcl, 64);
                unsigned v1 = (unsigned)__shfl((int)psrc[2 * ks2 + 1][et][jr & 1], srcl, 64);
                tmp[jr] = (q >> 1) ? v1 : v0;
            }
            U4H8 pf;
            pf.u.x = tmp[0]; pf.u.y = tmp[1]; pf.u.z = tmp[2]; pf.u.w = tmp[3];
#pragma unroll
            for (int nt = 0; nt < 4; ++nt)
                acc2[et][nt] = __builtin_amdgcn_mfma_f32_16x16x32_f16(
                    pf.h, wb[nt].h, acc2[et][nt], 0, 0, 0);
        }
    }

    // ---- segmented reduce; f16 agg: 2B stores interior, pk atomics at
    // boundaries ----
#pragma unroll
    for (int hf = 0; hf < 2; ++hf) {
#pragma unroll
        for (int et = 0; et < 4; ++et)
#pragma unroll
            for (int t2 = 0; t2 < 2; ++t2) {
                int nt = 2 * hf + t2;
                int cl = t2 * 16 + n15;
                int eb = et * 16 + q * 4;
#pragma unroll
                for (int r = 0; r < 4; ++r)
                    Mbuf[wid][(eb + r) * 33 + cl] = acc2[et][nt][r];
            }
        __syncthreads();
        {
            int cl = lane & 31, st = lane >> 5;
            int col = hf * 32 + cl;
            int ebase = 32 * st;
            float run = Mbuf[wid][ebase * 33 + cl];
            int runkey = ckey_s[wid][ebase];
            bool atstart = true;
#pragma unroll
            for (int i = 1; i < 32; ++i) {
                float v = Mbuf[wid][(ebase + i) * 33 + cl];
                if ((m32 >> i) & 1u) {
                    if (atstart) {
                        __half2 hv = (col & 1)
                            ? __floats2half2_rn(0.0f, run)
                            : __floats2half2_rn(run, 0.0f);
                        unsafeAtomicAdd(
                            (__half2*)agg + ((size_t)runkey << 5) + (col >> 1), hv);
                    } else {
                        agg[((size_t)runkey << 6) + col] = __float2half(run);
                    }
                    runkey = ckey_s[wid][ebase + i]; atstart = false;
                    run = v;
                } else {
                    run += v;
                }
            }
            __half2 hv = (col & 1)
                ? __floats2half2_rn(0.0f, run)
                : __floats2half2_rn(run, 0.0f);
            unsafeAtomicAdd((__half2*)agg + ((size_t)runkey << 5) + (col >> 1), hv);
        }
        __syncthreads();
    }
}

// MFMA upd kernel: 16 nodes per wave, 256-thr blocks. Residual in xh (f16);
// agg is f16 -> direct uint4 B-frag loads. Optional fused head + agg zero.
__global__ __launch_bounds__(256) void upd_k(
    unsigned* __restrict__ xh,
    __half* __restrict__ agg,
    const unsigned* __restrict__ w1t, const float* __restrict__ b1,
    const unsigned* __restrict__ w2t, const float* __restrict__ b2,
    const unsigned* __restrict__ ehw1t, const float* __restrict__ ehb1,
    const float* __restrict__ ehw2, const float* __restrict__ ehb2,
    const int* __restrict__ batch, float* __restrict__ energy,
    int do_zero, int do_head)
{
    __shared__ unsigned MU[4][16 * 33];   // per-wave f16-pair staging
    __shared__ float esum[NGRAPH];

    const int tid = threadIdx.x;
    const int wid = tid >> 6;
    const int lane = tid & 63;
    const int q = lane >> 4, n15 = lane & 15;
    const int base16 = blockIdx.x * 64 + wid * 16;   // wave's first node

    if (do_head) {
        if (tid < NGRAPH) esum[tid] = 0.0f;
        __syncthreads();
    }

    int nodeB = base16 + n15;
    int ncB = (nodeB < NN) ? nodeB : (NN - 1);

    // ---- GEMM1: H^T = W1T @ u_in^T, K=128, single node tile ----
    f32x4 acc1[4];
#pragma unroll
    for (int mt = 0; mt < 4; ++mt)
        acc1[mt] = *(const f32x4*)(b1 + mt * 16 + q * 4);
#pragma unroll
    for (int ks = 0; ks < 4; ++ks) {
        U4H8 bfk;
        if (ks < 2) {
            bfk.u = ((const uint4*)(xh + ((size_t)ncB << 5)))[ks * 4 + q];
        } else {
            bfk.u = ((const uint4*)(agg + ((size_t)ncB << 6)))[(ks - 2) * 4 + q];
        }
#pragma unroll
        for (int mt = 0; mt < 4; ++mt) {
            U4H8 af;
            af.u = *(const uint4*)(w1t + (size_t)(mt * 16 + n15) * 64 + ks * 16 + q * 4);
            acc1[mt] = __builtin_amdgcn_mfma_f32_16x16x32_f16(
                af.h, bfk.h, acc1[mt], 0, 0, 0);
        }
    }

    // ---- silu + pack ----
    unsigned psrc[4][2];
#pragma unroll
    for (int mt = 0; mt < 4; ++mt) {
        psrc[mt][0] = pk2(silu_f(acc1[mt][0]), silu_f(acc1[mt][1]));
        psrc[mt][1] = pk2(silu_f(acc1[mt][2]), silu_f(acc1[mt][3]));
    }

    // ---- GEMM2: out = P @ W2, K=64 ----
    f32x4 acc2[4];
#pragma unroll
    for (int nt = 0; nt < 4; ++nt) {
        float b2v = b2[nt * 16 + n15];
        acc2[nt][0] = b2v; acc2[nt][1] = b2v; acc2[nt][2] = b2v; acc2[nt][3] = b2v;
    }
#pragma unroll
    for (int ks2 = 0; ks2 < 2; ++ks2) {
        unsigned tmp[4];
#pragma unroll
        for (int jr = 0; jr < 4; ++jr) {
            int srcl = (2 * (q & 1) + (jr >> 1)) * 16 + n15;
            unsigned v0 = (unsigned)__shfl((int)psrc[2 * ks2][jr & 1], srcl, 64);
            unsigned v1 = (unsigned)__shfl((int)psrc[2 * ks2 + 1][jr & 1], srcl, 64);
            tmp[jr] = (q >> 1) ? v1 : v0;
        }
        U4H8 pf;
        pf.u.x = tmp[0]; pf.u.y = tmp[1]; pf.u.z = tmp[2]; pf.u.w = tmp[3];
#pragma unroll
        for (int nt = 0; nt < 4; ++nt) {
            U4H8 wb;
            wb.u = *(const uint4*)(w2t + (size_t)(nt * 16 + n15) * 32 + ks2 * 16 + q * 4);
            acc2[nt] = __builtin_amdgcn_mfma_f32_16x16x32_f16(
                pf.h, wb.h, acc2[nt], 0, 0, 0);
        }
    }

    // ---- epilogue: xh += out (f16 residual), pairs via shfl_xor ----
    // acc2[nt][r] = out[node = base16+4q+r][feat = 16nt+n15]
#pragma unroll
    for (int nt = 0; nt < 4; ++nt) {
#pragma unroll
        for (int r = 0; r < 4; ++r) {
            int node = base16 + 4 * q + r;
            float vnew = 0.0f;
            if (node < NN) {
                unsigned pu = xh[((size_t)node << 5) + (unsigned)((nt * 16 + n15) >> 1)];
                half2_t hp = u2h(pu);
                float vold = (n15 & 1) ? (float)hp[1] : (float)hp[0];
                vnew = vold + acc2[nt][r];
            }
            float vpart = __shfl_xor(vnew, 1, 64);
            if ((n15 & 1) == 0) {
                unsigned pv = pk2(vnew, vpart);
                int pidx = nt * 8 + (n15 >> 1);
                MU[wid][(4 * q + r) * 33 + pidx] = pv;
                if (node < NN) xh[((size_t)node << 5) + pidx] = pv;
            }
        }
    }

    if (do_zero) {   // re-zero this node's agg row (f16: 8 uint4)
        if (nodeB < NN) {
            uint4 z4; z4.x = z4.y = z4.z = z4.w = 0;
            uint4* ap = (uint4*)(agg + ((size_t)nodeB << 6));
            ap[2*q] = z4; ap[2*q + 1] = z4;
        }
    }

    if (do_head) {
        __syncthreads();   // MU visibility
        f32x4 acch[4];
#pragma unroll
        for (int mt = 0; mt < 4; ++mt)
            acch[mt] = *(const f32x4*)(ehb1 + mt * 16 + q * 4);
#pragma unroll
        for (int ks = 0; ks < 2; ++ks) {
            U4H8 bfk;
            bfk.u.x = MU[wid][n15 * 33 + ks * 16 + 4 * q + 0];
            bfk.u.y = MU[wid][n15 * 33 + ks * 16 + 4 * q + 1];
            bfk.u.z = MU[wid][n15 * 33 + ks * 16 + 4 * q + 2];
            bfk.u.w = MU[wid][n15 * 33 + ks * 16 + 4 * q + 3];
#pragma unroll
            for (int mt = 0; mt < 4; ++mt) {
                U4H8 af;
                af.u = *(const uint4*)(ehw1t + (size_t)(mt * 16 + n15) * 32 + ks * 16 + q * 4);
                acch[mt] = __builtin_amdgcn_mfma_f32_16x16x32_f16(
                    af.h, bfk.h, acch[mt], 0, 0, 0);
            }
        }
        f32x4 wv[4];
#pragma unroll
        for (int mt = 0; mt < 4; ++mt)
            wv[mt] = *(const f32x4*)(ehw2 + mt * 16 + q * 4);
        float e = 0.0f;
#pragma unroll
        for (int mt = 0; mt < 4; ++mt)
#pragma unroll
            for (int r = 0; r < 4; ++r)
                e = fmaf(silu_f(acch[mt][r]), wv[mt][r], e);
        e += __shfl_xor(e, 16, 64);
        e += __shfl_xor(e, 32, 64);
        if (q == 0) {
            int node = base16 + n15;
            if (node < NN) atomicAdd(&esum[batch[node]], e + ehb2[0]);
        }
        __syncthreads();
        if (tid < NGRAPH) {
            float v = esum[tid];
            if (v != 0.0f) atomicAdd(energy + tid, v);
        }
    }
}

extern "C" void kernel_launch(void* const* d_in, const int* in_sizes, int n_in,
                              void* d_out, int out_size, void* d_ws, size_t ws_size,
                              hipStream_t stream) {
    const int*   z       = (const int*)  d_in[0];
    const float* pos     = (const float*)d_in[1];
    const int*   eidx    = (const int*)  d_in[2];
    const int*   batch   = (const int*)  d_in[3];
    const float* embed   = (const float*)d_in[4];
    const float* msg_w1  = (const float*)d_in[5];
    const float* msg_b1  = (const float*)d_in[6];
    const float* msg_w2  = (const float*)d_in[7];
    const float* msg_b2  = (const float*)d_in[8];
    const float* upd_w1  = (const float*)d_in[9];
    const float* upd_b1  = (const float*)d_in[10];
    const float* upd_w2  = (const float*)d_in[11];
    const float* upd_b2  = (const float*)d_in[12];
    const float* eh_w1   = (const float*)d_in[13];
    const float* eh_b1   = (const float*)d_in[14];
    const float* eh_w2   = (const float*)d_in[15];
    const float* eh_b2   = (const float*)d_in[16];

    const int* erow = eidx;
    const int* ecol = eidx + EE;

    // ws layout (4-byte units); edgeS offset is 16B-aligned
    // agg region kept at NN*HH floats for layout stability; used as f16
    float*    aggf   = (float*)d_ws;                      // NN*64 (f16 used)
    unsigned* xh     = (unsigned*)(aggf + (size_t)NN * HH);// NN*32
    int*      deg    = (int*)(xh + (size_t)NN * 32);      // NN
    int*      cursor = deg + NN;                          // NN
    int*      bsum   = cursor + NN;                       // 64
    uint4*    edgeS  = (uint4*)(bsum + 64);               // EE uint4
    unsigned* w1t    = (unsigned*)(edgeS + EE);           // NL*64*80
    unsigned* w2t    = w1t + NLAYER * 64 * 80;            // NL*64*32
    unsigned* w1tu   = w2t + NLAYER * 64 * 32;            // NL*64*64
    unsigned* w2tu   = w1tu + NLAYER * 64 * 64;           // NL*64*32
    unsigned* ehw1t  = w2tu + NLAYER * 64 * 32;           // 64*32
    __half*   agg    = (__half*)aggf;
    float*    energy = (float*)d_out;

    (void)hipMemsetAsync(energy, 0, NGRAPH * sizeof(float), stream);
    (void)hipMemsetAsync(deg, 0, NN * sizeof(int), stream);
    (void)hipMemsetAsync(agg, 0, (size_t)NN * HH * sizeof(__half), stream);

    prep_k<<<9487, 256, 0, stream>>>(
        z, embed, xh,
        msg_w1, msg_w2, upd_w1, upd_w2, eh_w1,
        w1t, w2t, w1tu, w2tu, ehw1t,
        ecol, deg);

    scan1_k<<<NBLK1, 1024, 0, stream>>>(deg, cursor, bsum);
    scan2_k<<<1, 64, 0, stream>>>(bsum);
    scatter_k<<<(EE + 255) / 256, 256, 0, stream>>>(
        erow, ecol, pos, cursor, bsum, edgeS);

    for (int l = 0; l < NLAYER; ++l) {
        msg_k<<<EE / 256, 256, 0, stream>>>(
            edgeS, xh,
            w1t + (size_t)l * 64 * 80,
            msg_b1 + (size_t)l * HH,
            w2t + (size_t)l * 64 * 32,
            msg_b2 + (size_t)l * HH,
            agg);
        upd_k<<<(NN + 63) / 64, 256, 0, stream>>>(
            xh, agg,
            w1tu + (size_t)l * 64 * 64,
            upd_b1 + (size_t)l * HH,
            w2tu + (size_t)l * 64 * 32,
            upd_b2 + (size_t)l * HH,
            ehw1t, eh_b1, eh_w2, eh_b2, batch, energy,
            (l == 0) ? 1 : 0,            // re-zero agg for next layer
            (l == NLAYER - 1) ? 1 : 0);  // fused head on last layer
    }
}

// Round 16
// 383.076 us; speedup vs baseline: 1.1115x; 1.1115x over previous
//
#include <hip/hip_runtime.h>
#include <math.h>

#define NN 50000
#define EE 800000
#define HH 64
#define NBASIS 8
#define NLAYER 2
#define NGRAPH 64
#define NBLK1 49  // ceil(NN/1024)

using half2_t = decltype(__builtin_amdgcn_cvt_pkrtz(0.0f, 0.0f));
typedef _Float16 f16x8 __attribute__((ext_vector_type(8)));
typedef float f32x4 __attribute__((ext_vector_type(4)));

union U4H8 { uint4 u; f16x8 h; };

__device__ __forceinline__ float silu_f(float v) {
    return v * (1.0f / (1.0f + __expf(-v)));
}

__device__ __forceinline__ unsigned pk2(float a, float b) {
    union { half2_t h; unsigned u; } x;
    x.h = __builtin_amdgcn_cvt_pkrtz(a, b);
    return x.u;
}

__device__ __forceinline__ half2_t u2h(unsigned u) {
    union { unsigned u; half2_t h; } x; x.u = u; return x.h;
}

// fused prep: embed gather (blocks 0..6249), weight prepack (6250..6361),
// degree count (6362..9486), agg zero (9487..12611).
__global__ __launch_bounds__(256) void prep_k(
    const int* __restrict__ z, const float* __restrict__ embed,
    unsigned* __restrict__ xh,
    const float* __restrict__ msg_w1, const float* __restrict__ msg_w2,
    const float* __restrict__ upd_w1, const float* __restrict__ upd_w2,
    const float* __restrict__ eh_w1,
    unsigned* __restrict__ w1t, unsigned* __restrict__ w2t,
    unsigned* __restrict__ w1tu, unsigned* __restrict__ w2tu,
    unsigned* __restrict__ ehw1t,
    const int* __restrict__ ecol, int* __restrict__ deg,
    float4* __restrict__ agg4)
{
    int b = blockIdx.x;
    if (b < 6250) {                       // embed gather: NN*32 pairs
        int idx = b * 256 + threadIdx.x;  // < 1,600,000 always
        int n = idx >> 5;
        int p = idx & 31;
        const float2* er = (const float2*)(embed + ((size_t)z[n] << 6));
        float2 v = er[p];
        xh[idx] = pk2(v.x, v.y);
    } else if (b < 6362) {                // weight prepack, 28672 threads
        int idx = (b - 6250) * 256 + threadIdx.x;
        if (idx < 10240) {                    // msg w1t [l][f 64][kp 80]
            int l = idx / 5120, rem = idx % 5120;
            int f = rem / 80, kp = rem % 80;
            const float* w = msg_w1 + (size_t)l * 136 * 64;
            unsigned v = 0;
            if (kp < 68) v = pk2(w[(2*kp)*64 + f], w[(2*kp+1)*64 + f]);
            w1t[idx] = v;
        } else if (idx < 14336) {             // msg w2t [l][n 64][kp 32]
            int j = idx - 10240;
            int l = j / 2048, rem = j % 2048;
            int n = rem / 32, kp = rem % 32;
            const float* w = msg_w2 + (size_t)l * 64 * 64;
            w2t[j] = pk2(w[(2*kp)*64 + n], w[(2*kp+1)*64 + n]);
        } else if (idx < 22528) {             // upd w1tu [l][f 64][kp 64]
            int j = idx - 14336;
            int l = j / 4096, rem = j % 4096;
            int f = rem >> 6, kp = rem & 63;
            const float* w = upd_w1 + (size_t)l * 128 * 64;
            w1tu[j] = pk2(w[(2*kp)*64 + f], w[(2*kp+1)*64 + f]);
        } else if (idx < 26624) {             // upd w2tu [l][n 64][kp 32]
            int j = idx - 22528;
            int l = j / 2048, rem = j % 2048;
            int n = rem / 32, kp = rem % 32;
            const float* w = upd_w2 + (size_t)l * 64 * 64;
            w2tu[j] = pk2(w[(2*kp)*64 + n], w[(2*kp+1)*64 + n]);
        } else if (idx < 28672) {             // head ehw1t [f 64][kp 32]
            int j = idx - 26624;
            int f = j / 32, kp = j % 32;
            ehw1t[j] = pk2(eh_w1[(2*kp)*64 + f], eh_w1[(2*kp+1)*64 + f]);
        }
    } else if (b < 9487) {                // degree count
        int e = (b - 6362) * 256 + threadIdx.x;
        if (e < EE) atomicAdd(&deg[ecol[e]], 1);
    } else {                              // agg zero: NN*16 float4
        int idx = (b - 9487) * 256 + threadIdx.x;
        if (idx < NN * 16) {
            float4 z4; z4.x = z4.y = z4.z = z4.w = 0.0f;
            agg4[idx] = z4;
        }
    }
}

__global__ __launch_bounds__(1024) void scan1_k(
    const int* __restrict__ deg, int* __restrict__ cursor,
    int* __restrict__ bsum)
{
    __shared__ int wsum[16];
    int t = threadIdx.x, lane = t & 63, wave = t >> 6;
    int i = blockIdx.x * 1024 + t;
    int v = (i < NN) ? deg[i] : 0;
    int s = v;
#pragma unroll
    for (int off = 1; off < 64; off <<= 1) {
        int tv = __shfl_up(s, off, 64);
        if (lane >= off) s += tv;
    }
    if (lane == 63) wsum[wave] = s;
    __syncthreads();
    if (wave == 0) {
        int ws = (lane < 16) ? wsum[lane] : 0;
        int ss = ws;
#pragma unroll
        for (int off = 1; off < 16; off <<= 1) {
            int tv = __shfl_up(ss, off, 64);
            if (lane >= off) ss += tv;
        }
        if (lane < 16) wsum[lane] = ss - ws;
    }
    __syncthreads();
    int excl = wsum[wave] + s - v;
    if (i < NN) cursor[i] = excl;     // block-local exclusive scan
    if (t == 1023) bsum[blockIdx.x] = excl + v;
}

__global__ __launch_bounds__(64) void scan2_k(int* __restrict__ bsum)
{
    int lane = threadIdx.x;
    int v = (lane < NBLK1) ? bsum[lane] : 0;
    int s = v;
#pragma unroll
    for (int off = 1; off < 64; off <<= 1) {
        int tv = __shfl_up(s, off, 64);
        if (lane >= off) s += tv;
    }
    if (lane < NBLK1) bsum[lane] = s - v;
}

// scatter: one interleaved uint4 {row, col, d_bits, 0} per sorted slot
__global__ __launch_bounds__(256) void scatter_k(
    const int* __restrict__ erow, const int* __restrict__ ecol,
    const float* __restrict__ pos,
    int* __restrict__ cursor, const int* __restrict__ bsum,
    uint4* __restrict__ edgeS)
{
    int e = blockIdx.x * 256 + threadIdx.x;
    if (e >= EE) return;
    int c = ecol[e], r = erow[e];
    int slot = atomicAdd(&cursor[c], 1) + bsum[c >> 10];
    float dx = pos[3*r]   - pos[3*c];
    float dy = pos[3*r+1] - pos[3*c+1];
    float dz = pos[3*r+2] - pos[3*c+2];
    float d = sqrtf(dx*dx + dy*dy + dz*dz);
    uint4 v;
    v.x = (unsigned)r; v.y = (unsigned)c;
    v.z = __float_as_uint(d); v.w = 0;
    edgeS[slot] = v;
}

// MFMA msg kernel: 256-thread blocks = 4 private waves x 64 sorted edges.
// Barriers kept — they time-synchronize the block's 4 waves over adjacent
// sorted-edge chunks, keeping overlapping gathers/boundary agg lines
// L2-resident (r13: removing them cost +24%). (256,4): live regs ~128/wave
// (r11: tighter bound spills). agg stays fp32-word granularity (r15: f16
// stores/atomics caused partial-line write amplification, +63% WRITE).
__global__ __launch_bounds__(256, 4) void msg_k(
    const uint4* __restrict__ edgeS,
    const unsigned* __restrict__ xh,
    const unsigned* __restrict__ w1t, const float* __restrict__ b1,
    const unsigned* __restrict__ w2t, const float* __restrict__ b2,
    float* __restrict__ agg)
{
    __shared__ __align__(16) unsigned earr[4][64 * 4];
    __shared__ int ckey_s[4][64];
    __shared__ int rkey_s[4][64];
    __shared__ float Mbuf[4][64 * 33];

    const int wid  = threadIdx.x >> 6;
    const int lane = threadIdx.x & 63;
    const int q = lane >> 4, n15 = lane & 15;
    const size_t base = (size_t)blockIdx.x * 256 + wid * 64;

    int mykey;
    // ---- per-edge prep (single coalesced 16B read) ----
    {
        uint4 ev = edgeS[base + lane];
        rkey_s[wid][lane] = (int)ev.x;
        mykey = (int)ev.y;
        ckey_s[wid][lane] = mykey;
        float d = __uint_as_float(ev.z);
        float env = 0.0f;
        if (d < 5.0f) {
            float cv = __cosf(d * 0.31415926535897932f);  // pi/(2*CUTOFF)
            env = cv * cv;
        }
        float scale = (d > 0.0f) ? (env / d) : env;
        float ea[NBASIS];
#pragma unroll
        for (int k = 0; k < NBASIS; ++k)
            ea[k] = __sinf((float)(k + 1) * 0.62831853071795865f * d) * scale;
#pragma unroll
        for (int p = 0; p < 4; ++p)
            earr[wid][lane * 4 + p] = pk2(ea[2*p], ea[2*p+1]);
    }
    // boundary bitmask: bit L set iff key[L] != key[L-1]
    int pkk = __shfl_up(mykey, 1, 64);
    unsigned long long bmask = __ballot(lane > 0 && mykey != pkk);
    unsigned m32 = (unsigned)(bmask >> (lane & 32));  // my strip's 32 bits
    __syncthreads();

    int cn[4], rn[4];
#pragma unroll
    for (int nt = 0; nt < 4; ++nt) {
        int eB = nt * 16 + n15;
        cn[nt] = ckey_s[wid][eB];
        rn[nt] = rkey_s[wid][eB];
    }

    // ---- GEMM1, frags streamed per ks ----
    f32x4 acc1[4][4];
#pragma unroll
    for (int mt = 0; mt < 4; ++mt) {
        f32x4 binit = *(const f32x4*)(b1 + mt * 16 + q * 4);
#pragma unroll
        for (int nt = 0; nt < 4; ++nt) acc1[mt][nt] = binit;
    }
#pragma unroll
    for (int ks = 0; ks < 5; ++ks) {
        U4H8 bfk[4];
#pragma unroll
        for (int nt = 0; nt < 4; ++nt) {
            if (ks == 4) {
                uint4 zz; zz.x = zz.y = zz.z = zz.w = 0;
                bfk[nt].u = (q == 0) ? *(const uint4*)(earr[wid] + (nt * 16 + n15) * 4) : zz;
            } else if (ks < 2) {
                bfk[nt].u = ((const uint4*)(xh + ((size_t)cn[nt] << 5)))[ks * 4 + q];
            } else {
                bfk[nt].u = ((const uint4*)(xh + ((size_t)rn[nt] << 5)))[(ks - 2) * 4 + q];
            }
        }
#pragma unroll
        for (int mt = 0; mt < 4; ++mt) {
            U4H8 af;
            af.u = *(const uint4*)(w1t + (size_t)(mt * 16 + n15) * 80 + ks * 16 + q * 4);
#pragma unroll
            for (int nt = 0; nt < 4; ++nt)
                acc1[mt][nt] = __builtin_amdgcn_mfma_f32_16x16x32_f16(
                    af.h, bfk[nt].h, acc1[mt][nt], 0, 0, 0);
        }
    }

    // ---- silu + pack ----
    unsigned psrc[4][4][2];
#pragma unroll
    for (int mt = 0; mt < 4; ++mt)
#pragma unroll
        for (int nt = 0; nt < 4; ++nt) {
            psrc[mt][nt][0] = pk2(silu_f(acc1[mt][nt][0]), silu_f(acc1[mt][nt][1]));
            psrc[mt][nt][1] = pk2(silu_f(acc1[mt][nt][2]), silu_f(acc1[mt][nt][3]));
        }

    // ---- GEMM2 ----
    f32x4 acc2[4][4];
#pragma unroll
    for (int nt = 0; nt < 4; ++nt) {
        float b2v = b2[nt * 16 + n15];
        f32x4 binit; binit[0] = b2v; binit[1] = b2v; binit[2] = b2v; binit[3] = b2v;
#pragma unroll
        for (int et = 0; et < 4; ++et) acc2[et][nt] = binit;
    }
#pragma unroll
    for (int ks2 = 0; ks2 < 2; ++ks2) {
        U4H8 wb[4];
#pragma unroll
        for (int nt = 0; nt < 4; ++nt)
            wb[nt].u = *(const uint4*)(w2t + (size_t)(nt * 16 + n15) * 32 + ks2 * 16 + q * 4);
#pragma unroll
        for (int et = 0; et < 4; ++et) {
            unsigned tmp[4];
#pragma unroll
            for (int jr = 0; jr < 4; ++jr) {
                int srcl = (2 * (q & 1) + (jr >> 1)) * 16 + n15;
                unsigned v0 = (unsigned)__shfl((int)psrc[2 * ks2][et][jr & 1], srcl, 64);
                unsigned v1 = (unsigned)__shfl((int)psrc[2 * ks2 + 1][et][jr & 1], srcl, 64);
                tmp[jr] = (q >> 1) ? v1 : v0;
            }
            U4H8 pf;
            pf.u.x = tmp[0]; pf.u.y = tmp[1]; pf.u.z = tmp[2]; pf.u.w = tmp[3];
#pragma unroll
            for (int nt = 0; nt < 4; ++nt)
                acc2[et][nt] = __builtin_amdgcn_mfma_f32_16x16x32_f16(
                    pf.h, wb[nt].h, acc2[et][nt], 0, 0, 0);
        }
    }

    // ---- segmented reduce; boundary bitmask, key reads only at flips ----
#pragma unroll
    for (int hf = 0; hf < 2; ++hf) {
#pragma unroll
        for (int et = 0; et < 4; ++et)
#pragma unroll
            for (int t2 = 0; t2 < 2; ++t2) {
                int nt = 2 * hf + t2;
                int cl = t2 * 16 + n15;
                int eb = et * 16 + q * 4;
#pragma unroll
                for (int r = 0; r < 4; ++r)
                    Mbuf[wid][(eb + r) * 33 + cl] = acc2[et][nt][r];
            }
        __syncthreads();
        {
            int cl = lane & 31, st = lane >> 5;
            int ebase = 32 * st;
            float run = Mbuf[wid][ebase * 33 + cl];
            int runkey = ckey_s[wid][ebase];
            bool atstart = true;
#pragma unroll
            for (int i = 1; i < 32; ++i) {
                float v = Mbuf[wid][(ebase + i) * 33 + cl];
                if ((m32 >> i) & 1u) {
                    float* dst = agg + ((size_t)runkey << 6) + hf * 32 + cl;
                    if (atstart) atomicAdd(dst, run); else *dst = run;
                    runkey = ckey_s[wid][ebase + i]; atstart = false;
                    run = v;
                } else {
                    run += v;
                }
            }
            atomicAdd(agg + ((size_t)runkey << 6) + hf * 32 + cl, run);
        }
        __syncthreads();
    }
}

// MFMA upd kernel: 16 nodes per wave, 256-thr blocks. Residual lives in xh
// (f16): epilogue reads old pair, adds, re-packs. Optional fused head and
// agg re-zero.
__global__ __launch_bounds__(256) void upd_k(
    unsigned* __restrict__ xh,
    float* __restrict__ agg,
    const unsigned* __restrict__ w1t, const float* __restrict__ b1,
    const unsigned* __restrict__ w2t, const float* __restrict__ b2,
    const unsigned* __restrict__ ehw1t, const float* __restrict__ ehb1,
    const float* __restrict__ ehw2, const float* __restrict__ ehb2,
    const int* __restrict__ batch, float* __restrict__ energy,
    int do_zero, int do_head)
{
    __shared__ unsigned MU[4][16 * 33];   // per-wave f16-pair staging
    __shared__ float esum[NGRAPH];

    const int tid = threadIdx.x;
    const int wid = tid >> 6;
    const int lane = tid & 63;
    const int q = lane >> 4, n15 = lane & 15;
    const int base16 = blockIdx.x * 64 + wid * 16;   // wave's first node

    if (do_head) {
        if (tid < NGRAPH) esum[tid] = 0.0f;
        __syncthreads();
    }

    int nodeB = base16 + n15;
    int ncB = (nodeB < NN) ? nodeB : (NN - 1);

    // ---- GEMM1: H^T = W1T @ u_in^T, K=128, single node tile ----
    f32x4 acc1[4];
#pragma unroll
    for (int mt = 0; mt < 4; ++mt)
        acc1[mt] = *(const f32x4*)(b1 + mt * 16 + q * 4);
#pragma unroll
    for (int ks = 0; ks < 4; ++ks) {
        U4H8 bfk;
        if (ks < 2) {
            bfk.u = ((const uint4*)(xh + ((size_t)ncB << 5)))[ks * 4 + q];
        } else {
            const float4* ap = (const float4*)(agg + ((size_t)ncB << 6));
            int o = (ks - 2) * 8 + 2 * q;
            float4 a0 = ap[o], a1 = ap[o + 1];
            bfk.u.x = pk2(a0.x, a0.y); bfk.u.y = pk2(a0.z, a0.w);
            bfk.u.z = pk2(a1.x, a1.y); bfk.u.w = pk2(a1.z, a1.w);
        }
#pragma unroll
        for (int mt = 0; mt < 4; ++mt) {
            U4H8 af;
            af.u = *(const uint4*)(w1t + (size_t)(mt * 16 + n15) * 64 + ks * 16 + q * 4);
            acc1[mt] = __builtin_amdgcn_mfma_f32_16x16x32_f16(
                af.h, bfk.h, acc1[mt], 0, 0, 0);
        }
    }

    // ---- silu + pack ----
    unsigned psrc[4][2];
#pragma unroll
    for (int mt = 0; mt < 4; ++mt) {
        psrc[mt][0] = pk2(silu_f(acc1[mt][0]), silu_f(acc1[mt][1]));
        psrc[mt][1] = pk2(silu_f(acc1[mt][2]), silu_f(acc1[mt][3]));
    }

    // ---- GEMM2: out = P @ W2, K=64 ----
    f32x4 acc2[4];
#pragma unroll
    for (int nt = 0; nt < 4; ++nt) {
        float b2v = b2[nt * 16 + n15];
        acc2[nt][0] = b2v; acc2[nt][1] = b2v; acc2[nt][2] = b2v; acc2[nt][3] = b2v;
    }
#pragma unroll
    for (int ks2 = 0; ks2 < 2; ++ks2) {
        unsigned tmp[4];
#pragma unroll
        for (int jr = 0; jr < 4; ++jr) {
            int srcl = (2 * (q & 1) + (jr >> 1)) * 16 + n15;
            unsigned v0 = (unsigned)__shfl((int)psrc[2 * ks2][jr & 1], srcl, 64);
            unsigned v1 = (unsigned)__shfl((int)psrc[2 * ks2 + 1][jr & 1], srcl, 64);
            tmp[jr] = (q >> 1) ? v1 : v0;
        }
        U4H8 pf;
        pf.u.x = tmp[0]; pf.u.y = tmp[1]; pf.u.z = tmp[2]; pf.u.w = tmp[3];
#pragma unroll
        for (int nt = 0; nt < 4; ++nt) {
            U4H8 wb;
            wb.u = *(const uint4*)(w2t + (size_t)(nt * 16 + n15) * 32 + ks2 * 16 + q * 4);
            acc2[nt] = __builtin_amdgcn_mfma_f32_16x16x32_f16(
                pf.h, wb.h, acc2[nt], 0, 0, 0);
        }
    }

    // ---- epilogue: xh += out (f16 residual), pairs via shfl_xor ----
    // acc2[nt][r] = out[node = base16+4q+r][feat = 16nt+n15]
#pragma unroll
    for (int nt = 0; nt < 4; ++nt) {
#pragma unroll
        for (int r = 0; r < 4; ++r) {
            int node = base16 + 4 * q + r;
            float vnew = 0.0f;
            if (node < NN) {
                unsigned pu = xh[((size_t)node << 5) + (unsigned)((nt * 16 + n15) >> 1)];
                half2_t hp = u2h(pu);
                float vold = (n15 & 1) ? (float)hp[1] : (float)hp[0];
                vnew = vold + acc2[nt][r];
            }
            float vpart = __shfl_xor(vnew, 1, 64);
            if ((n15 & 1) == 0) {
                unsigned pv = pk2(vnew, vpart);
                int pidx = nt * 8 + (n15 >> 1);
                MU[wid][(4 * q + r) * 33 + pidx] = pv;
                if (node < NN) xh[((size_t)node << 5) + pidx] = pv;
            }
        }
    }

    if (do_zero) {   // re-zero exactly the agg chunks this lane read
        if (nodeB < NN) {
            float4 z4; z4.x = z4.y = z4.z = z4.w = 0.0f;
            float4* ap = (float4*)(agg + ((size_t)nodeB << 6));
            ap[2*q] = z4; ap[2*q + 1] = z4;
            ap[8 + 2*q] = z4; ap[8 + 2*q + 1] = z4;
        }
    }

    if (do_head) {
        __syncthreads();   // MU visibility
        f32x4 acch[4];
#pragma unroll
        for (int mt = 0; mt < 4; ++mt)
            acch[mt] = *(const f32x4*)(ehb1 + mt * 16 + q * 4);
#pragma unroll
        for (int ks = 0; ks < 2; ++ks) {
            U4H8 bfk;
            bfk.u.x = MU[wid][n15 * 33 + ks * 16 + 4 * q + 0];
            bfk.u.y = MU[wid][n15 * 33 + ks * 16 + 4 * q + 1];
            bfk.u.z = MU[wid][n15 * 33 + ks * 16 + 4 * q + 2];
            bfk.u.w = MU[wid][n15 * 33 + ks * 16 + 4 * q + 3];
#pragma unroll
            for (int mt = 0; mt < 4; ++mt) {
                U4H8 af;
                af.u = *(const uint4*)(ehw1t + (size_t)(mt * 16 + n15) * 32 + ks * 16 + q * 4);
                acch[mt] = __builtin_amdgcn_mfma_f32_16x16x32_f16(
                    af.h, bfk.h, acch[mt], 0, 0, 0);
            }
        }
        f32x4 wv[4];
#pragma unroll
        for (int mt = 0; mt < 4; ++mt)
            wv[mt] = *(const f32x4*)(ehw2 + mt * 16 + q * 4);
        float e = 0.0f;
#pragma unroll
        for (int mt = 0; mt < 4; ++mt)
#pragma unroll
            for (int r = 0; r < 4; ++r)
                e = fmaf(silu_f(acch[mt][r]), wv[mt][r], e);
        e += __shfl_xor(e, 16, 64);
        e += __shfl_xor(e, 32, 64);
        if (q == 0) {
            int node = base16 + n15;
            if (node < NN) atomicAdd(&esum[batch[node]], e + ehb2[0]);
        }
        __syncthreads();
        if (tid < NGRAPH) {
            float v = esum[tid];
            if (v != 0.0f) atomicAdd(energy + tid, v);
        }
    }
}

extern "C" void kernel_launch(void* const* d_in, const int* in_sizes, int n_in,
                              void* d_out, int out_size, void* d_ws, size_t ws_size,
                              hipStream_t stream) {
    const int*   z       = (const int*)  d_in[0];
    const float* pos     = (const float*)d_in[1];
    const int*   eidx    = (const int*)  d_in[2];
    const int*   batch   = (const int*)  d_in[3];
    const float* embed   = (const float*)d_in[4];
    const float* msg_w1  = (const float*)d_in[5];
    const float* msg_b1  = (const float*)d_in[6];
    const float* msg_w2  = (const float*)d_in[7];
    const float* msg_b2  = (const float*)d_in[8];
    const float* upd_w1  = (const float*)d_in[9];
    const float* upd_b1  = (const float*)d_in[10];
    const float* upd_w2  = (const float*)d_in[11];
    const float* upd_b2  = (const float*)d_in[12];
    const float* eh_w1   = (const float*)d_in[13];
    const float* eh_b1   = (const float*)d_in[14];
    const float* eh_w2   = (const float*)d_in[15];
    const float* eh_b2   = (const float*)d_in[16];

    const int* erow = eidx;
    const int* ecol = eidx + EE;

    // ws layout (4-byte units); edgeS offset is 16B-aligned
    float*    agg    = (float*)d_ws;                      // NN*64
    unsigned* xh     = (unsigned*)(agg + (size_t)NN * HH);// NN*32
    int*      deg    = (int*)(xh + (size_t)NN * 32);      // NN
    int*      cursor = deg + NN;                          // NN
    int*      bsum   = cursor + NN;                       // 64
    uint4*    edgeS  = (uint4*)(bsum + 64);               // EE uint4
    unsigned* w1t    = (unsigned*)(edgeS + EE);           // NL*64*80
    unsigned* w2t    = w1t + NLAYER * 64 * 80;            // NL*64*32
    unsigned* w1tu   = w2t + NLAYER * 64 * 32;            // NL*64*64
    unsigned* w2tu   = w1tu + NLAYER * 64 * 64;           // NL*64*32
    unsigned* ehw1t  = w2tu + NLAYER * 64 * 32;           // 64*32
    float*    energy = (float*)d_out;

    (void)hipMemsetAsync(energy, 0, NGRAPH * sizeof(float), stream);
    (void)hipMemsetAsync(deg, 0, NN * sizeof(int), stream);

    // prep also zeroes agg (blocks 9487..12611): NN*16 float4 = 3125 blocks
    prep_k<<<12612, 256, 0, stream>>>(
        z, embed, xh,
        msg_w1, msg_w2, upd_w1, upd_w2, eh_w1,
        w1t, w2t, w1tu, w2tu, ehw1t,
        ecol, deg, (float4*)agg);

    scan1_k<<<NBLK1, 1024, 0, stream>>>(deg, cursor, bsum);
    scan2_k<<<1, 64, 0, stream>>>(bsum);
    scatter_k<<<(EE + 255) / 256, 256, 0, stream>>>(
        erow, ecol, pos, cursor, bsum, edgeS);

    for (int l = 0; l < NLAYER; ++l) {
        msg_k<<<EE / 256, 256, 0, stream>>>(
            edgeS, xh,
            w1t + (size_t)l * 64 * 80,
            msg_b1 + (size_t)l * HH,
            w2t + (size_t)l * 64 * 32,
            msg_b2 + (size_t)l * HH,
            agg);
        upd_k<<<(NN + 63) / 64, 256, 0, stream>>>(
            xh, agg,
            w1tu + (size_t)l * 64 * 64,
            upd_b1 + (size_t)l * HH,
            w2tu + (size_t)l * 64 * 32,
            upd_b2 + (size_t)l * HH,
            ehw1t, eh_b1, eh_w2, eh_b2, batch, energy,
            (l == 0) ? 1 : 0,            // re-zero agg for next layer
            (l == NLAYER - 1) ? 1 : 0);  // fused head on last layer
    }
}

// Round 17
// 377.633 us; speedup vs baseline: 1.1275x; 1.0144x over previous
//
#include <hip/hip_runtime.h>
#include <math.h>

#define NN 50000
#define EE 800000
#define HH 64
#define NBASIS 8
#define NLAYER 2
#define NGRAPH 64
#define NBLK1 49  // ceil(NN/1024)

using half2_t = decltype(__builtin_amdgcn_cvt_pkrtz(0.0f, 0.0f));
typedef _Float16 f16x8 __attribute__((ext_vector_type(8)));
typedef float f32x4 __attribute__((ext_vector_type(4)));

union U4H8 { uint4 u; f16x8 h; };

__device__ __forceinline__ float silu_f(float v) {
    return v * (1.0f / (1.0f + __expf(-v)));
}

__device__ __forceinline__ unsigned pk2(float a, float b) {
    union { half2_t h; unsigned u; } x;
    x.h = __builtin_amdgcn_cvt_pkrtz(a, b);
    return x.u;
}

__device__ __forceinline__ half2_t u2h(unsigned u) {
    union { unsigned u; half2_t h; } x; x.u = u; return x.h;
}

// fused prep: embed gather (blocks 0..6249), weight prepack (6250..6361),
// degree count (6362..9486), agg zero (9487..12611).
__global__ __launch_bounds__(256) void prep_k(
    const int* __restrict__ z, const float* __restrict__ embed,
    unsigned* __restrict__ xh,
    const float* __restrict__ msg_w1, const float* __restrict__ msg_w2,
    const float* __restrict__ upd_w1, const float* __restrict__ upd_w2,
    const float* __restrict__ eh_w1,
    unsigned* __restrict__ w1t, unsigned* __restrict__ w2t,
    unsigned* __restrict__ w1tu, unsigned* __restrict__ w2tu,
    unsigned* __restrict__ ehw1t,
    const int* __restrict__ ecol, int* __restrict__ deg,
    float4* __restrict__ agg4)
{
    int b = blockIdx.x;
    if (b < 6250) {                       // embed gather: NN*32 pairs
        int idx = b * 256 + threadIdx.x;  // < 1,600,000 always
        int n = idx >> 5;
        int p = idx & 31;
        const float2* er = (const float2*)(embed + ((size_t)z[n] << 6));
        float2 v = er[p];
        xh[idx] = pk2(v.x, v.y);
    } else if (b < 6362) {                // weight prepack, 28672 threads
        int idx = (b - 6250) * 256 + threadIdx.x;
        if (idx < 10240) {                    // msg w1t [l][f 64][kp 80]
            int l = idx / 5120, rem = idx % 5120;
            int f = rem / 80, kp = rem % 80;
            const float* w = msg_w1 + (size_t)l * 136 * 64;
            unsigned v = 0;
            if (kp < 68) v = pk2(w[(2*kp)*64 + f], w[(2*kp+1)*64 + f]);
            w1t[idx] = v;
        } else if (idx < 14336) {             // msg w2t [l][n 64][kp 32]
            int j = idx - 10240;
            int l = j / 2048, rem = j % 2048;
            int n = rem / 32, kp = rem % 32;
            const float* w = msg_w2 + (size_t)l * 64 * 64;
            w2t[j] = pk2(w[(2*kp)*64 + n], w[(2*kp+1)*64 + n]);
        } else if (idx < 22528) {             // upd w1tu [l][f 64][kp 64]
            int j = idx - 14336;
            int l = j / 4096, rem = j % 4096;
            int f = rem >> 6, kp = rem & 63;
            const float* w = upd_w1 + (size_t)l * 128 * 64;
            w1tu[j] = pk2(w[(2*kp)*64 + f], w[(2*kp+1)*64 + f]);
        } else if (idx < 26624) {             // upd w2tu [l][n 64][kp 32]
            int j = idx - 22528;
            int l = j / 2048, rem = j % 2048;
            int n = rem / 32, kp = rem % 32;
            const float* w = upd_w2 + (size_t)l * 64 * 64;
            w2tu[j] = pk2(w[(2*kp)*64 + n], w[(2*kp+1)*64 + n]);
        } else if (idx < 28672) {             // head ehw1t [f 64][kp 32]
            int j = idx - 26624;
            int f = j / 32, kp = j % 32;
            ehw1t[j] = pk2(eh_w1[(2*kp)*64 + f], eh_w1[(2*kp+1)*64 + f]);
        }
    } else if (b < 9487) {                // degree count
        int e = (b - 6362) * 256 + threadIdx.x;
        if (e < EE) atomicAdd(&deg[ecol[e]], 1);
    } else {                              // agg zero: NN*16 float4
        int idx = (b - 9487) * 256 + threadIdx.x;
        if (idx < NN * 16) {
            float4 z4; z4.x = z4.y = z4.z = z4.w = 0.0f;
            agg4[idx] = z4;
        }
    }
}

__global__ __launch_bounds__(1024) void scan1_k(
    const int* __restrict__ deg, int* __restrict__ cursor,
    int* __restrict__ bsum)
{
    __shared__ int wsum[16];
    int t = threadIdx.x, lane = t & 63, wave = t >> 6;
    int i = blockIdx.x * 1024 + t;
    int v = (i < NN) ? deg[i] : 0;
    int s = v;
#pragma unroll
    for (int off = 1; off < 64; off <<= 1) {
        int tv = __shfl_up(s, off, 64);
        if (lane >= off) s += tv;
    }
    if (lane == 63) wsum[wave] = s;
    __syncthreads();
    if (wave == 0) {
        int ws = (lane < 16) ? wsum[lane] : 0;
        int ss = ws;
#pragma unroll
        for (int off = 1; off < 16; off <<= 1) {
            int tv = __shfl_up(ss, off, 64);
            if (lane >= off) ss += tv;
        }
        if (lane < 16) wsum[lane] = ss - ws;
    }
    __syncthreads();
    int excl = wsum[wave] + s - v;
    if (i < NN) cursor[i] = excl;     // block-local exclusive scan
    if (t == 1023) bsum[blockIdx.x] = excl + v;
}

__global__ __launch_bounds__(64) void scan2_k(int* __restrict__ bsum)
{
    int lane = threadIdx.x;
    int v = (lane < NBLK1) ? bsum[lane] : 0;
    int s = v;
#pragma unroll
    for (int off = 1; off < 64; off <<= 1) {
        int tv = __shfl_up(s, off, 64);
        if (lane >= off) s += tv;
    }
    if (lane < NBLK1) bsum[lane] = s - v;
}

// scatter: 8B per sorted slot — {row<<16|col, d_bits} (NN < 2^16).
__global__ __launch_bounds__(256) void scatter_k(
    const int* __restrict__ erow, const int* __restrict__ ecol,
    const float* __restrict__ pos,
    int* __restrict__ cursor, const int* __restrict__ bsum,
    uint2* __restrict__ edgeS)
{
    int e = blockIdx.x * 256 + threadIdx.x;
    if (e >= EE) return;
    int c = ecol[e], r = erow[e];
    int slot = atomicAdd(&cursor[c], 1) + bsum[c >> 10];
    float dx = pos[3*r]   - pos[3*c];
    float dy = pos[3*r+1] - pos[3*c+1];
    float dz = pos[3*r+2] - pos[3*c+2];
    float d = sqrtf(dx*dx + dy*dy + dz*dz);
    uint2 v;
    v.x = ((unsigned)r << 16) | (unsigned)c;
    v.y = __float_as_uint(d);
    edgeS[slot] = v;
}

// MFMA msg kernel: 256-thread blocks = 4 private waves x 64 sorted edges.
// Barriers kept — they time-synchronize the block's 4 waves over adjacent
// sorted-edge chunks, keeping overlapping gathers/boundary agg lines
// L2-resident (r13: removing them cost +24%). (256,4): live regs ~128/wave
// (r11: tighter bound spills). agg stays fp32-word granularity (r15: f16
// stores/atomics caused partial-line write amplification, +63% WRITE).
// LDS bank-conflict fixes (r17): Mbuf stride 34 (write bank 8q+2r+n15 ->
// exact 2-way = free), earr transposed to [p][lane] (bank = lane -> free),
// rkey via shfl at a convergent point (frees 1KB; ckey_s kept for the
// divergent reduce-phase reads).
__global__ __launch_bounds__(256, 4) void msg_k(
    const uint2* __restrict__ edgeS,
    const unsigned* __restrict__ xh,
    const unsigned* __restrict__ w1t, const float* __restrict__ b1,
    const unsigned* __restrict__ w2t, const float* __restrict__ b2,
    float* __restrict__ agg)
{
    __shared__ unsigned earrT[4][4 * 64];   // [wid][p*64 + lane]
    __shared__ int ckey_s[4][64];
    __shared__ float Mbuf[4][64 * 34];

    const int wid  = threadIdx.x >> 6;
    const int lane = threadIdx.x & 63;
    const int q = lane >> 4, n15 = lane & 15;
    const size_t base = (size_t)blockIdx.x * 256 + wid * 64;

    uint2 ev = edgeS[base + lane];
    int myrow = (int)(ev.x >> 16);
    int mykey = (int)(ev.x & 0xffffu);
    ckey_s[wid][lane] = mykey;

    // ---- per-edge radial basis ----
    {
        float d = __uint_as_float(ev.y);
        float env = 0.0f;
        if (d < 5.0f) {
            float cv = __cosf(d * 0.31415926535897932f);  // pi/(2*CUTOFF)
            env = cv * cv;
        }
        float scale = (d > 0.0f) ? (env / d) : env;
        float ea[NBASIS];
#pragma unroll
        for (int k = 0; k < NBASIS; ++k)
            ea[k] = __sinf((float)(k + 1) * 0.62831853071795865f * d) * scale;
#pragma unroll
        for (int p = 0; p < 4; ++p)
            earrT[wid][p * 64 + lane] = pk2(ea[2*p], ea[2*p+1]);
    }
    // boundary bitmask: bit L set iff key[L] != key[L-1]
    int pkk = __shfl_up(mykey, 1, 64);
    unsigned long long bmask = __ballot(lane > 0 && mykey != pkk);
    unsigned m32 = (unsigned)(bmask >> (lane & 32));  // my strip's 32 bits

    // cross-lane keys for B-columns via shfl (convergent point, wave-local)
    int cn[4], rn[4];
#pragma unroll
    for (int nt = 0; nt < 4; ++nt) {
        cn[nt] = __shfl(mykey, nt * 16 + n15, 64);
        rn[nt] = __shfl(myrow, nt * 16 + n15, 64);
    }
    __syncthreads();

    // ---- GEMM1, frags streamed per ks ----
    f32x4 acc1[4][4];
#pragma unroll
    for (int mt = 0; mt < 4; ++mt) {
        f32x4 binit = *(const f32x4*)(b1 + mt * 16 + q * 4);
#pragma unroll
        for (int nt = 0; nt < 4; ++nt) acc1[mt][nt] = binit;
    }
#pragma unroll
    for (int ks = 0; ks < 5; ++ks) {
        U4H8 bfk[4];
#pragma unroll
        for (int nt = 0; nt < 4; ++nt) {
            if (ks == 4) {
                int eB = nt * 16 + n15;
                unsigned e0 = earrT[wid][0 * 64 + eB];
                unsigned e1 = earrT[wid][1 * 64 + eB];
                unsigned e2 = earrT[wid][2 * 64 + eB];
                unsigned e3 = earrT[wid][3 * 64 + eB];
                bfk[nt].u.x = (q == 0) ? e0 : 0u;
                bfk[nt].u.y = (q == 0) ? e1 : 0u;
                bfk[nt].u.z = (q == 0) ? e2 : 0u;
                bfk[nt].u.w = (q == 0) ? e3 : 0u;
            } else if (ks < 2) {
                bfk[nt].u = ((const uint4*)(xh + ((size_t)cn[nt] << 5)))[ks * 4 + q];
            } else {
                bfk[nt].u = ((const uint4*)(xh + ((size_t)rn[nt] << 5)))[(ks - 2) * 4 + q];
            }
        }
#pragma unroll
        for (int mt = 0; mt < 4; ++mt) {
            U4H8 af;
            af.u = *(const uint4*)(w1t + (size_t)(mt * 16 + n15) * 80 + ks * 16 + q * 4);
#pragma unroll
            for (int nt = 0; nt < 4; ++nt)
                acc1[mt][nt] = __builtin_amdgcn_mfma_f32_16x16x32_f16(
                    af.h, bfk[nt].h, acc1[mt][nt], 0, 0, 0);
        }
    }

    // ---- silu + pack ----
    unsigned psrc[4][4][2];
#pragma unroll
    for (int mt = 0; mt < 4; ++mt)
#pragma unroll
        for (int nt = 0; nt < 4; ++nt) {
            psrc[mt][nt][0] = pk2(silu_f(acc1[mt][nt][0]), silu_f(acc1[mt][nt][1]));
            psrc[mt][nt][1] = pk2(silu_f(acc1[mt][nt][2]), silu_f(acc1[mt][nt][3]));
        }

    // ---- GEMM2 ----
    f32x4 acc2[4][4];
#pragma unroll
    for (int nt = 0; nt < 4; ++nt) {
        float b2v = b2[nt * 16 + n15];
        f32x4 binit; binit[0] = b2v; binit[1] = b2v; binit[2] = b2v; binit[3] = b2v;
#pragma unroll
        for (int et = 0; et < 4; ++et) acc2[et][nt] = binit;
    }
#pragma unroll
    for (int ks2 = 0; ks2 < 2; ++ks2) {
        U4H8 wb[4];
#pragma unroll
        for (int nt = 0; nt < 4; ++nt)
            wb[nt].u = *(const uint4*)(w2t + (size_t)(nt * 16 + n15) * 32 + ks2 * 16 + q * 4);
#pragma unroll
        for (int et = 0; et < 4; ++et) {
            unsigned tmp[4];
#pragma unroll
            for (int jr = 0; jr < 4; ++jr) {
                int srcl = (2 * (q & 1) + (jr >> 1)) * 16 + n15;
                unsigned v0 = (unsigned)__shfl((int)psrc[2 * ks2][et][jr & 1], srcl, 64);
                unsigned v1 = (unsigned)__shfl((int)psrc[2 * ks2 + 1][et][jr & 1], srcl, 64);
                tmp[jr] = (q >> 1) ? v1 : v0;
            }
            U4H8 pf;
            pf.u.x = tmp[0]; pf.u.y = tmp[1]; pf.u.z = tmp[2]; pf.u.w = tmp[3];
#pragma unroll
            for (int nt = 0; nt < 4; ++nt)
                acc2[et][nt] = __builtin_amdgcn_mfma_f32_16x16x32_f16(
                    pf.h, wb[nt].h, acc2[et][nt], 0, 0, 0);
        }
    }

    // ---- segmented reduce; boundary bitmask, key reads only at flips ----
#pragma unroll
    for (int hf = 0; hf < 2; ++hf) {
#pragma unroll
        for (int et = 0; et < 4; ++et)
#pragma unroll
            for (int t2 = 0; t2 < 2; ++t2) {
                int nt = 2 * hf + t2;
                int cl = t2 * 16 + n15;
                int eb = et * 16 + q * 4;
#pragma unroll
                for (int r = 0; r < 4; ++r)
                    Mbuf[wid][(eb + r) * 34 + cl] = acc2[et][nt][r];
            }
        __syncthreads();
        {
            int cl = lane & 31, st = lane >> 5;
            int ebase = 32 * st;
            float run = Mbuf[wid][ebase * 34 + cl];
            int runkey = ckey_s[wid][ebase];
            bool atstart = true;
#pragma unroll
            for (int i = 1; i < 32; ++i) {
                float v = Mbuf[wid][(ebase + i) * 34 + cl];
                if ((m32 >> i) & 1u) {
                    float* dst = agg + ((size_t)runkey << 6) + hf * 32 + cl;
                    if (atstart) atomicAdd(dst, run); else *dst = run;
                    runkey = ckey_s[wid][ebase + i]; atstart = false;
                    run = v;
                } else {
                    run += v;
                }
            }
            atomicAdd(agg + ((size_t)runkey << 6) + hf * 32 + cl, run);
        }
        __syncthreads();
    }
}

// MFMA upd kernel: 16 nodes per wave, 256-thr blocks. Residual lives in xh
// (f16): epilogue reads old pair, adds, re-packs. Optional fused head and
// agg re-zero.
__global__ __launch_bounds__(256) void upd_k(
    unsigned* __restrict__ xh,
    float* __restrict__ agg,
    const unsigned* __restrict__ w1t, const float* __restrict__ b1,
    const unsigned* __restrict__ w2t, const float* __restrict__ b2,
    const unsigned* __restrict__ ehw1t, const float* __restrict__ ehb1,
    const float* __restrict__ ehw2, const float* __restrict__ ehb2,
    const int* __restrict__ batch, float* __restrict__ energy,
    int do_zero, int do_head)
{
    __shared__ unsigned MU[4][16 * 33];   // per-wave f16-pair staging
    __shared__ float esum[NGRAPH];

    const int tid = threadIdx.x;
    const int wid = tid >> 6;
    const int lane = tid & 63;
    const int q = lane >> 4, n15 = lane & 15;
    const int base16 = blockIdx.x * 64 + wid * 16;   // wave's first node

    if (do_head) {
        if (tid < NGRAPH) esum[tid] = 0.0f;
        __syncthreads();
    }

    int nodeB = base16 + n15;
    int ncB = (nodeB < NN) ? nodeB : (NN - 1);

    // ---- GEMM1: H^T = W1T @ u_in^T, K=128, single node tile ----
    f32x4 acc1[4];
#pragma unroll
    for (int mt = 0; mt < 4; ++mt)
        acc1[mt] = *(const f32x4*)(b1 + mt * 16 + q * 4);
#pragma unroll
    for (int ks = 0; ks < 4; ++ks) {
        U4H8 bfk;
        if (ks < 2) {
            bfk.u = ((const uint4*)(xh + ((size_t)ncB << 5)))[ks * 4 + q];
        } else {
            const float4* ap = (const float4*)(agg + ((size_t)ncB << 6));
            int o = (ks - 2) * 8 + 2 * q;
            float4 a0 = ap[o], a1 = ap[o + 1];
            bfk.u.x = pk2(a0.x, a0.y); bfk.u.y = pk2(a0.z, a0.w);
            bfk.u.z = pk2(a1.x, a1.y); bfk.u.w = pk2(a1.z, a1.w);
        }
#pragma unroll
        for (int mt = 0; mt < 4; ++mt) {
            U4H8 af;
            af.u = *(const uint4*)(w1t + (size_t)(mt * 16 + n15) * 64 + ks * 16 + q * 4);
            acc1[mt] = __builtin_amdgcn_mfma_f32_16x16x32_f16(
                af.h, bfk.h, acc1[mt], 0, 0, 0);
        }
    }

    // ---- silu + pack ----
    unsigned psrc[4][2];
#pragma unroll
    for (int mt = 0; mt < 4; ++mt) {
        psrc[mt][0] = pk2(silu_f(acc1[mt][0]), silu_f(acc1[mt][1]));
        psrc[mt][1] = pk2(silu_f(acc1[mt][2]), silu_f(acc1[mt][3]));
    }

    // ---- GEMM2: out = P @ W2, K=64 ----
    f32x4 acc2[4];
#pragma unroll
    for (int nt = 0; nt < 4; ++nt) {
        float b2v = b2[nt * 16 + n15];
        acc2[nt][0] = b2v; acc2[nt][1] = b2v; acc2[nt][2] = b2v; acc2[nt][3] = b2v;
    }
#pragma unroll
    for (int ks2 = 0; ks2 < 2; ++ks2) {
        unsigned tmp[4];
#pragma unroll
        for (int jr = 0; jr < 4; ++jr) {
            int srcl = (2 * (q & 1) + (jr >> 1)) * 16 + n15;
            unsigned v0 = (unsigned)__shfl((int)psrc[2 * ks2][jr & 1], srcl, 64);
            unsigned v1 = (unsigned)__shfl((int)psrc[2 * ks2 + 1][jr & 1], srcl, 64);
            tmp[jr] = (q >> 1) ? v1 : v0;
        }
        U4H8 pf;
        pf.u.x = tmp[0]; pf.u.y = tmp[1]; pf.u.z = tmp[2]; pf.u.w = tmp[3];
#pragma unroll
        for (int nt = 0; nt < 4; ++nt) {
            U4H8 wb;
            wb.u = *(const uint4*)(w2t + (size_t)(nt * 16 + n15) * 32 + ks2 * 16 + q * 4);
            acc2[nt] = __builtin_amdgcn_mfma_f32_16x16x32_f16(
                pf.h, wb.h, acc2[nt], 0, 0, 0);
        }
    }

    // ---- epilogue: xh += out (f16 residual), pairs via shfl_xor ----
    // acc2[nt][r] = out[node = base16+4q+r][feat = 16nt+n15]
#pragma unroll
    for (int nt = 0; nt < 4; ++nt) {
#pragma unroll
        for (int r = 0; r < 4; ++r) {
            int node = base16 + 4 * q + r;
            float vnew = 0.0f;
            if (node < NN) {
                unsigned pu = xh[((size_t)node << 5) + (unsigned)((nt * 16 + n15) >> 1)];
                half2_t hp = u2h(pu);
                float vold = (n15 & 1) ? (float)hp[1] : (float)hp[0];
                vnew = vold + acc2[nt][r];
            }
            float vpart = __shfl_xor(vnew, 1, 64);
            if ((n15 & 1) == 0) {
                unsigned pv = pk2(vnew, vpart);
                int pidx = nt * 8 + (n15 >> 1);
                MU[wid][(4 * q + r) * 33 + pidx] = pv;
                if (node < NN) xh[((size_t)node << 5) + pidx] = pv;
            }
        }
    }

    if (do_zero) {   // re-zero exactly the agg chunks this lane read
        if (nodeB < NN) {
            float4 z4; z4.x = z4.y = z4.z = z4.w = 0.0f;
            float4* ap = (float4*)(agg + ((size_t)nodeB << 6));
            ap[2*q] = z4; ap[2*q + 1] = z4;
            ap[8 + 2*q] = z4; ap[8 + 2*q + 1] = z4;
        }
    }

    if (do_head) {
        __syncthreads();   // MU visibility
        f32x4 acch[4];
#pragma unroll
        for (int mt = 0; mt < 4; ++mt)
            acch[mt] = *(const f32x4*)(ehb1 + mt * 16 + q * 4);
#pragma unroll
        for (int ks = 0; ks < 2; ++ks) {
            U4H8 bfk;
            bfk.u.x = MU[wid][n15 * 33 + ks * 16 + 4 * q + 0];
            bfk.u.y = MU[wid][n15 * 33 + ks * 16 + 4 * q + 1];
            bfk.u.z = MU[wid][n15 * 33 + ks * 16 + 4 * q + 2];
            bfk.u.w = MU[wid][n15 * 33 + ks * 16 + 4 * q + 3];
#pragma unroll
            for (int mt = 0; mt < 4; ++mt) {
                U4H8 af;
                af.u = *(const uint4*)(ehw1t + (size_t)(mt * 16 + n15) * 32 + ks * 16 + q * 4);
                acch[mt] = __builtin_amdgcn_mfma_f32_16x16x32_f16(
                    af.h, bfk.h, acch[mt], 0, 0, 0);
            }
        }
        f32x4 wv[4];
#pragma unroll
        for (int mt = 0; mt < 4; ++mt)
            wv[mt] = *(const f32x4*)(ehw2 + mt * 16 + q * 4);
        float e = 0.0f;
#pragma unroll
        for (int mt = 0; mt < 4; ++mt)
#pragma unroll
            for (int r = 0; r < 4; ++r)
                e = fmaf(silu_f(acch[mt][r]), wv[mt][r], e);
        e += __shfl_xor(e, 16, 64);
        e += __shfl_xor(e, 32, 64);
        if (q == 0) {
            int node = base16 + n15;
            if (node < NN) atomicAdd(&esum[batch[node]], e + ehb2[0]);
        }
        __syncthreads();
        if (tid < NGRAPH) {
            float v = esum[tid];
            if (v != 0.0f) atomicAdd(energy + tid, v);
        }
    }
}

extern "C" void kernel_launch(void* const* d_in, const int* in_sizes, int n_in,
                              void* d_out, int out_size, void* d_ws, size_t ws_size,
                              hipStream_t stream) {
    const int*   z       = (const int*)  d_in[0];
    const float* pos     = (const float*)d_in[1];
    const int*   eidx    = (const int*)  d_in[2];
    const int*   batch   = (const int*)  d_in[3];
    const float* embed   = (const float*)d_in[4];
    const float* msg_w1  = (const float*)d_in[5];
    const float* msg_b1  = (const float*)d_in[6];
    const float* msg_w2  = (const float*)d_in[7];
    const float* msg_b2  = (const float*)d_in[8];
    const float* upd_w1  = (const float*)d_in[9];
    const float* upd_b1  = (const float*)d_in[10];
    const float* upd_w2  = (const float*)d_in[11];
    const float* upd_b2  = (const float*)d_in[12];
    const float* eh_w1   = (const float*)d_in[13];
    const float* eh_b1   = (const float*)d_in[14];
    const float* eh_w2   = (const float*)d_in[15];
    const float* eh_b2   = (const float*)d_in[16];

    const int* erow = eidx;
    const int* ecol = eidx + EE;

    // ws layout (4-byte units); edgeS offset is 8B-aligned
    float*    agg    = (float*)d_ws;                      // NN*64
    unsigned* xh     = (unsigned*)(agg + (size_t)NN * HH);// NN*32
    int*      deg    = (int*)(xh + (size_t)NN * 32);      // NN
    int*      cursor = deg + NN;                          // NN
    int*      bsum   = cursor + NN;                       // 64
    uint2*    edgeS  = (uint2*)(bsum + 64);               // EE uint2 (8B)
    unsigned* w1t    = (unsigned*)(edgeS + EE);           // NL*64*80
    unsigned* w2t    = w1t + NLAYER * 64 * 80;            // NL*64*32
    unsigned* w1tu   = w2t + NLAYER * 64 * 32;            // NL*64*64
    unsigned* w2tu   = w1tu + NLAYER * 64 * 64;           // NL*64*32
    unsigned* ehw1t  = w2tu + NLAYER * 64 * 32;           // 64*32
    float*    energy = (float*)d_out;

    (void)hipMemsetAsync(energy, 0, NGRAPH * sizeof(float), stream);
    (void)hipMemsetAsync(deg, 0, NN * sizeof(int), stream);

    // prep also zeroes agg (blocks 9487..12611): NN*16 float4 = 3125 blocks
    prep_k<<<12612, 256, 0, stream>>>(
        z, embed, xh,
        msg_w1, msg_w2, upd_w1, upd_w2, eh_w1,
        w1t, w2t, w1tu, w2tu, ehw1t,
        ecol, deg, (float4*)agg);

    scan1_k<<<NBLK1, 1024, 0, stream>>>(deg, cursor, bsum);
    scan2_k<<<1, 64, 0, stream>>>(bsum);
    scatter_k<<<(EE + 255) / 256, 256, 0, stream>>>(
        erow, ecol, pos, cursor, bsum, edgeS);

    for (int l = 0; l < NLAYER; ++l) {
        msg_k<<<EE / 256, 256, 0, stream>>>(
            edgeS, xh,
            w1t + (size_t)l * 64 * 80,
            msg_b1 + (size_t)l * HH,
            w2t + (size_t)l * 64 * 32,
            msg_b2 + (size_t)l * HH,
            agg);
        upd_k<<<(NN + 63) / 64, 256, 0, stream>>>(
            xh, agg,
            w1tu + (size_t)l * 64 * 64,
            upd_b1 + (size_t)l * HH,
            w2tu + (size_t)l * 64 * 32,
            upd_b2 + (size_t)l * HH,
            ehw1t, eh_b1, eh_w2, eh_b2, batch, energy,
            (l == 0) ? 1 : 0,            // re-zero agg for next layer
            (l == NLAYER - 1) ? 1 : 0);  // fused head on last layer
    }
}

// Round 18
// 374.326 us; speedup vs baseline: 1.1375x; 1.0088x over previous
//
#include <hip/hip_runtime.h>
#include <math.h>

#define NN 50000
#define EE 800000
#define HH 64
#define NBASIS 8
#define NLAYER 2
#define NGRAPH 64
#define NBLK1 49  // ceil(NN/1024)

using half2_t = decltype(__builtin_amdgcn_cvt_pkrtz(0.0f, 0.0f));
typedef _Float16 f16x8 __attribute__((ext_vector_type(8)));
typedef float f32x4 __attribute__((ext_vector_type(4)));

union U4H8 { uint4 u; f16x8 h; };

__device__ __forceinline__ float silu_f(float v) {
    return v * (1.0f / (1.0f + __expf(-v)));
}

__device__ __forceinline__ unsigned pk2(float a, float b) {
    union { half2_t h; unsigned u; } x;
    x.h = __builtin_amdgcn_cvt_pkrtz(a, b);
    return x.u;
}

__device__ __forceinline__ half2_t u2h(unsigned u) {
    union { unsigned u; half2_t h; } x; x.u = u; return x.h;
}

// fused prep: embed gather (blocks 0..6249), weight prepack (6250..6361),
// degree count (6362..9486), agg zero (9487..12611).
__global__ __launch_bounds__(256) void prep_k(
    const int* __restrict__ z, const float* __restrict__ embed,
    unsigned* __restrict__ xh,
    const float* __restrict__ msg_w1, const float* __restrict__ msg_w2,
    const float* __restrict__ upd_w1, const float* __restrict__ upd_w2,
    const float* __restrict__ eh_w1,
    unsigned* __restrict__ w1t, unsigned* __restrict__ w2t,
    unsigned* __restrict__ w1tu, unsigned* __restrict__ w2tu,
    unsigned* __restrict__ ehw1t,
    const int* __restrict__ ecol, int* __restrict__ deg,
    float4* __restrict__ agg4)
{
    int b = blockIdx.x;
    if (b < 6250) {                       // embed gather: NN*32 pairs
        int idx = b * 256 + threadIdx.x;  // < 1,600,000 always
        int n = idx >> 5;
        int p = idx & 31;
        const float2* er = (const float2*)(embed + ((size_t)z[n] << 6));
        float2 v = er[p];
        xh[idx] = pk2(v.x, v.y);
    } else if (b < 6362) {                // weight prepack, 28672 threads
        int idx = (b - 6250) * 256 + threadIdx.x;
        if (idx < 10240) {                    // msg w1t [l][f 64][kp 80]
            int l = idx / 5120, rem = idx % 5120;
            int f = rem / 80, kp = rem % 80;
            const float* w = msg_w1 + (size_t)l * 136 * 64;
            unsigned v = 0;
            if (kp < 68) v = pk2(w[(2*kp)*64 + f], w[(2*kp+1)*64 + f]);
            w1t[idx] = v;
        } else if (idx < 14336) {             // msg w2t [l][n 64][kp 32]
            int j = idx - 10240;
            int l = j / 2048, rem = j % 2048;
            int n = rem / 32, kp = rem % 32;
            const float* w = msg_w2 + (size_t)l * 64 * 64;
            w2t[j] = pk2(w[(2*kp)*64 + n], w[(2*kp+1)*64 + n]);
        } else if (idx < 22528) {             // upd w1tu [l][f 64][kp 64]
            int j = idx - 14336;
            int l = j / 4096, rem = j % 4096;
            int f = rem >> 6, kp = rem & 63;
            const float* w = upd_w1 + (size_t)l * 128 * 64;
            w1tu[j] = pk2(w[(2*kp)*64 + f], w[(2*kp+1)*64 + f]);
        } else if (idx < 26624) {             // upd w2tu [l][n 64][kp 32]
            int j = idx - 22528;
            int l = j / 2048, rem = j % 2048;
            int n = rem / 32, kp = rem % 32;
            const float* w = upd_w2 + (size_t)l * 64 * 64;
            w2tu[j] = pk2(w[(2*kp)*64 + n], w[(2*kp+1)*64 + n]);
        } else if (idx < 28672) {             // head ehw1t [f 64][kp 32]
            int j = idx - 26624;
            int f = j / 32, kp = j % 32;
            ehw1t[j] = pk2(eh_w1[(2*kp)*64 + f], eh_w1[(2*kp+1)*64 + f]);
        }
    } else if (b < 9487) {                // degree count
        int e = (b - 6362) * 256 + threadIdx.x;
        if (e < EE) atomicAdd(&deg[ecol[e]], 1);
    } else {                              // agg zero: NN*16 float4
        int idx = (b - 9487) * 256 + threadIdx.x;
        if (idx < NN * 16) {
            float4 z4; z4.x = z4.y = z4.z = z4.w = 0.0f;
            agg4[idx] = z4;
        }
    }
}

__global__ __launch_bounds__(1024) void scan1_k(
    const int* __restrict__ deg, int* __restrict__ cursor,
    int* __restrict__ bsum)
{
    __shared__ int wsum[16];
    int t = threadIdx.x, lane = t & 63, wave = t >> 6;
    int i = blockIdx.x * 1024 + t;
    int v = (i < NN) ? deg[i] : 0;
    int s = v;
#pragma unroll
    for (int off = 1; off < 64; off <<= 1) {
        int tv = __shfl_up(s, off, 64);
        if (lane >= off) s += tv;
    }
    if (lane == 63) wsum[wave] = s;
    __syncthreads();
    if (wave == 0) {
        int ws = (lane < 16) ? wsum[lane] : 0;
        int ss = ws;
#pragma unroll
        for (int off = 1; off < 16; off <<= 1) {
            int tv = __shfl_up(ss, off, 64);
            if (lane >= off) ss += tv;
        }
        if (lane < 16) wsum[lane] = ss - ws;
    }
    __syncthreads();
    int excl = wsum[wave] + s - v;
    if (i < NN) cursor[i] = excl;     // block-local exclusive scan
    if (t == 1023) bsum[blockIdx.x] = excl + v;
}

__global__ __launch_bounds__(64) void scan2_k(int* __restrict__ bsum)
{
    int lane = threadIdx.x;
    int v = (lane < NBLK1) ? bsum[lane] : 0;
    int s = v;
#pragma unroll
    for (int off = 1; off < 64; off <<= 1) {
        int tv = __shfl_up(s, off, 64);
        if (lane >= off) s += tv;
    }
    if (lane < NBLK1) bsum[lane] = s - v;
}

// scatter: 8B per sorted slot — {row<<16|col, d_bits} (NN < 2^16).
__global__ __launch_bounds__(256) void scatter_k(
    const int* __restrict__ erow, const int* __restrict__ ecol,
    const float* __restrict__ pos,
    int* __restrict__ cursor, const int* __restrict__ bsum,
    uint2* __restrict__ edgeS)
{
    int e = blockIdx.x * 256 + threadIdx.x;
    if (e >= EE) return;
    int c = ecol[e], r = erow[e];
    int slot = atomicAdd(&cursor[c], 1) + bsum[c >> 10];
    float dx = pos[3*r]   - pos[3*c];
    float dy = pos[3*r+1] - pos[3*c+1];
    float dz = pos[3*r+2] - pos[3*c+2];
    float d = sqrtf(dx*dx + dy*dy + dz*dz);
    uint2 v;
    v.x = ((unsigned)r << 16) | (unsigned)c;
    v.y = __float_as_uint(d);
    edgeS[slot] = v;
}

// MFMA msg kernel: 256-thread blocks = 4 private waves x 64 sorted edges.
// Barriers kept (r13: removing them de-synced waves, +24%). (256,4): live
// regs ~160/wave incl. row prefetch (r11: tighter bound spills). agg stays
// fp32-word granularity (r15: f16 caused write amplification). r18: random
// row gathers issued BEFORE the transcendental block (latency overlapped
// with sinf + GEMM1 col phase); barriers unchanged.
__global__ __launch_bounds__(256, 4) void msg_k(
    const uint2* __restrict__ edgeS,
    const unsigned* __restrict__ xh,
    const unsigned* __restrict__ w1t, const float* __restrict__ b1,
    const unsigned* __restrict__ w2t, const float* __restrict__ b2,
    float* __restrict__ agg)
{
    __shared__ unsigned earrT[4][4 * 64];   // [wid][p*64 + lane]
    __shared__ int ckey_s[4][64];
    __shared__ float Mbuf[4][64 * 34];

    const int wid  = threadIdx.x >> 6;
    const int lane = threadIdx.x & 63;
    const int q = lane >> 4, n15 = lane & 15;
    const size_t base = (size_t)blockIdx.x * 256 + wid * 64;

    uint2 ev = edgeS[base + lane];
    int myrow = (int)(ev.x >> 16);
    int mykey = (int)(ev.x & 0xffffu);
    ckey_s[wid][lane] = mykey;

    // cross-lane keys for B-columns via shfl (fully convergent point)
    int cn[4], rn[4];
#pragma unroll
    for (int nt = 0; nt < 4; ++nt) {
        cn[nt] = __shfl(mykey, nt * 16 + n15, 64);
        rn[nt] = __shfl(myrow, nt * 16 + n15, 64);
    }

    // issue the random row gathers NOW; latency overlaps sinf + col phase
    U4H8 bfr[2][4];
#pragma unroll
    for (int nt = 0; nt < 4; ++nt) {
        const uint4* rp = (const uint4*)(xh + ((size_t)rn[nt] << 5));
        bfr[0][nt].u = rp[q];
        bfr[1][nt].u = rp[4 + q];
    }

    // ---- per-edge radial basis (overlapped with row gathers) ----
    {
        float d = __uint_as_float(ev.y);
        float env = 0.0f;
        if (d < 5.0f) {
            float cv = __cosf(d * 0.31415926535897932f);  // pi/(2*CUTOFF)
            env = cv * cv;
        }
        float scale = (d > 0.0f) ? (env / d) : env;
        float ea[NBASIS];
#pragma unroll
        for (int k = 0; k < NBASIS; ++k)
            ea[k] = __sinf((float)(k + 1) * 0.62831853071795865f * d) * scale;
#pragma unroll
        for (int p = 0; p < 4; ++p)
            earrT[wid][p * 64 + lane] = pk2(ea[2*p], ea[2*p+1]);
    }
    // boundary bitmask: bit L set iff key[L] != key[L-1]
    int pkk = __shfl_up(mykey, 1, 64);
    unsigned long long bmask = __ballot(lane > 0 && mykey != pkk);
    unsigned m32 = (unsigned)(bmask >> (lane & 32));  // my strip's 32 bits
    __syncthreads();

    // ---- GEMM1, col frags streamed per ks; rows from prefetch ----
    f32x4 acc1[4][4];
#pragma unroll
    for (int mt = 0; mt < 4; ++mt) {
        f32x4 binit = *(const f32x4*)(b1 + mt * 16 + q * 4);
#pragma unroll
        for (int nt = 0; nt < 4; ++nt) acc1[mt][nt] = binit;
    }
#pragma unroll
    for (int ks = 0; ks < 5; ++ks) {
        U4H8 bfk[4];
#pragma unroll
        for (int nt = 0; nt < 4; ++nt) {
            if (ks == 4) {
                int eB = nt * 16 + n15;
                unsigned e0 = earrT[wid][0 * 64 + eB];
                unsigned e1 = earrT[wid][1 * 64 + eB];
                unsigned e2 = earrT[wid][2 * 64 + eB];
                unsigned e3 = earrT[wid][3 * 64 + eB];
                bfk[nt].u.x = (q == 0) ? e0 : 0u;
                bfk[nt].u.y = (q == 0) ? e1 : 0u;
                bfk[nt].u.z = (q == 0) ? e2 : 0u;
                bfk[nt].u.w = (q == 0) ? e3 : 0u;
            } else if (ks < 2) {
                bfk[nt].u = ((const uint4*)(xh + ((size_t)cn[nt] << 5)))[ks * 4 + q];
            } else {
                bfk[nt] = bfr[ks - 2][nt];
            }
        }
#pragma unroll
        for (int mt = 0; mt < 4; ++mt) {
            U4H8 af;
            af.u = *(const uint4*)(w1t + (size_t)(mt * 16 + n15) * 80 + ks * 16 + q * 4);
#pragma unroll
            for (int nt = 0; nt < 4; ++nt)
                acc1[mt][nt] = __builtin_amdgcn_mfma_f32_16x16x32_f16(
                    af.h, bfk[nt].h, acc1[mt][nt], 0, 0, 0);
        }
    }

    // ---- silu + pack ----
    unsigned psrc[4][4][2];
#pragma unroll
    for (int mt = 0; mt < 4; ++mt)
#pragma unroll
        for (int nt = 0; nt < 4; ++nt) {
            psrc[mt][nt][0] = pk2(silu_f(acc1[mt][nt][0]), silu_f(acc1[mt][nt][1]));
            psrc[mt][nt][1] = pk2(silu_f(acc1[mt][nt][2]), silu_f(acc1[mt][nt][3]));
        }

    // ---- GEMM2 ----
    f32x4 acc2[4][4];
#pragma unroll
    for (int nt = 0; nt < 4; ++nt) {
        float b2v = b2[nt * 16 + n15];
        f32x4 binit; binit[0] = b2v; binit[1] = b2v; binit[2] = b2v; binit[3] = b2v;
#pragma unroll
        for (int et = 0; et < 4; ++et) acc2[et][nt] = binit;
    }
#pragma unroll
    for (int ks2 = 0; ks2 < 2; ++ks2) {
        U4H8 wb[4];
#pragma unroll
        for (int nt = 0; nt < 4; ++nt)
            wb[nt].u = *(const uint4*)(w2t + (size_t)(nt * 16 + n15) * 32 + ks2 * 16 + q * 4);
#pragma unroll
        for (int et = 0; et < 4; ++et) {
            unsigned tmp[4];
#pragma unroll
            for (int jr = 0; jr < 4; ++jr) {
                int srcl = (2 * (q & 1) + (jr >> 1)) * 16 + n15;
                unsigned v0 = (unsigned)__shfl((int)psrc[2 * ks2][et][jr & 1], srcl, 64);
                unsigned v1 = (unsigned)__shfl((int)psrc[2 * ks2 + 1][et][jr & 1], srcl, 64);
                tmp[jr] = (q >> 1) ? v1 : v0;
            }
            U4H8 pf;
            pf.u.x = tmp[0]; pf.u.y = tmp[1]; pf.u.z = tmp[2]; pf.u.w = tmp[3];
#pragma unroll
            for (int nt = 0; nt < 4; ++nt)
                acc2[et][nt] = __builtin_amdgcn_mfma_f32_16x16x32_f16(
                    pf.h, wb[nt].h, acc2[et][nt], 0, 0, 0);
        }
    }

    // ---- segmented reduce; boundary bitmask, key reads only at flips ----
#pragma unroll
    for (int hf = 0; hf < 2; ++hf) {
#pragma unroll
        for (int et = 0; et < 4; ++et)
#pragma unroll
            for (int t2 = 0; t2 < 2; ++t2) {
                int nt = 2 * hf + t2;
                int cl = t2 * 16 + n15;
                int eb = et * 16 + q * 4;
#pragma unroll
                for (int r = 0; r < 4; ++r)
                    Mbuf[wid][(eb + r) * 34 + cl] = acc2[et][nt][r];
            }
        __syncthreads();
        {
            int cl = lane & 31, st = lane >> 5;
            int ebase = 32 * st;
            float run = Mbuf[wid][ebase * 34 + cl];
            int runkey = ckey_s[wid][ebase];
            bool atstart = true;
#pragma unroll
            for (int i = 1; i < 32; ++i) {
                float v = Mbuf[wid][(ebase + i) * 34 + cl];
                if ((m32 >> i) & 1u) {
                    float* dst = agg + ((size_t)runkey << 6) + hf * 32 + cl;
                    if (atstart) atomicAdd(dst, run); else *dst = run;
                    runkey = ckey_s[wid][ebase + i]; atstart = false;
                    run = v;
                } else {
                    run += v;
                }
            }
            atomicAdd(agg + ((size_t)runkey << 6) + hf * 32 + cl, run);
        }
        __syncthreads();
    }
}

// MFMA upd kernel: 16 nodes per wave, 256-thr blocks. Residual lives in xh
// (f16): epilogue reads old pair, adds, re-packs. Optional fused head and
// agg re-zero.
__global__ __launch_bounds__(256) void upd_k(
    unsigned* __restrict__ xh,
    float* __restrict__ agg,
    const unsigned* __restrict__ w1t, const float* __restrict__ b1,
    const unsigned* __restrict__ w2t, const float* __restrict__ b2,
    const unsigned* __restrict__ ehw1t, const float* __restrict__ ehb1,
    const float* __restrict__ ehw2, const float* __restrict__ ehb2,
    const int* __restrict__ batch, float* __restrict__ energy,
    int do_zero, int do_head)
{
    __shared__ unsigned MU[4][16 * 33];   // per-wave f16-pair staging
    __shared__ float esum[NGRAPH];

    const int tid = threadIdx.x;
    const int wid = tid >> 6;
    const int lane = tid & 63;
    const int q = lane >> 4, n15 = lane & 15;
    const int base16 = blockIdx.x * 64 + wid * 16;   // wave's first node

    if (do_head) {
        if (tid < NGRAPH) esum[tid] = 0.0f;
        __syncthreads();
    }

    int nodeB = base16 + n15;
    int ncB = (nodeB < NN) ? nodeB : (NN - 1);

    // ---- GEMM1: H^T = W1T @ u_in^T, K=128, single node tile ----
    f32x4 acc1[4];
#pragma unroll
    for (int mt = 0; mt < 4; ++mt)
        acc1[mt] = *(const f32x4*)(b1 + mt * 16 + q * 4);
#pragma unroll
    for (int ks = 0; ks < 4; ++ks) {
        U4H8 bfk;
        if (ks < 2) {
            bfk.u = ((const uint4*)(xh + ((size_t)ncB << 5)))[ks * 4 + q];
        } else {
            const float4* ap = (const float4*)(agg + ((size_t)ncB << 6));
            int o = (ks - 2) * 8 + 2 * q;
            float4 a0 = ap[o], a1 = ap[o + 1];
            bfk.u.x = pk2(a0.x, a0.y); bfk.u.y = pk2(a0.z, a0.w);
            bfk.u.z = pk2(a1.x, a1.y); bfk.u.w = pk2(a1.z, a1.w);
        }
#pragma unroll
        for (int mt = 0; mt < 4; ++mt) {
            U4H8 af;
            af.u = *(const uint4*)(w1t + (size_t)(mt * 16 + n15) * 64 + ks * 16 + q * 4);
            acc1[mt] = __builtin_amdgcn_mfma_f32_16x16x32_f16(
                af.h, bfk.h, acc1[mt], 0, 0, 0);
        }
    }

    // ---- silu + pack ----
    unsigned psrc[4][2];
#pragma unroll
    for (int mt = 0; mt < 4; ++mt) {
        psrc[mt][0] = pk2(silu_f(acc1[mt][0]), silu_f(acc1[mt][1]));
        psrc[mt][1] = pk2(silu_f(acc1[mt][2]), silu_f(acc1[mt][3]));
    }

    // ---- GEMM2: out = P @ W2, K=64 ----
    f32x4 acc2[4];
#pragma unroll
    for (int nt = 0; nt < 4; ++nt) {
        float b2v = b2[nt * 16 + n15];
        acc2[nt][0] = b2v; acc2[nt][1] = b2v; acc2[nt][2] = b2v; acc2[nt][3] = b2v;
    }
#pragma unroll
    for (int ks2 = 0; ks2 < 2; ++ks2) {
        unsigned tmp[4];
#pragma unroll
        for (int jr = 0; jr < 4; ++jr) {
            int srcl = (2 * (q & 1) + (jr >> 1)) * 16 + n15;
            unsigned v0 = (unsigned)__shfl((int)psrc[2 * ks2][jr & 1], srcl, 64);
            unsigned v1 = (unsigned)__shfl((int)psrc[2 * ks2 + 1][jr & 1], srcl, 64);
            tmp[jr] = (q >> 1) ? v1 : v0;
        }
        U4H8 pf;
        pf.u.x = tmp[0]; pf.u.y = tmp[1]; pf.u.z = tmp[2]; pf.u.w = tmp[3];
#pragma unroll
        for (int nt = 0; nt < 4; ++nt) {
            U4H8 wb;
            wb.u = *(const uint4*)(w2t + (size_t)(nt * 16 + n15) * 32 + ks2 * 16 + q * 4);
            acc2[nt] = __builtin_amdgcn_mfma_f32_16x16x32_f16(
                pf.h, wb.h, acc2[nt], 0, 0, 0);
        }
    }

    // ---- epilogue: xh += out (f16 residual), pairs via shfl_xor ----
    // acc2[nt][r] = out[node = base16+4q+r][feat = 16nt+n15]
#pragma unroll
    for (int nt = 0; nt < 4; ++nt) {
#pragma unroll
        for (int r = 0; r < 4; ++r) {
            int node = base16 + 4 * q + r;
            float vnew = 0.0f;
            if (node < NN) {
                unsigned pu = xh[((size_t)node << 5) + (unsigned)((nt * 16 + n15) >> 1)];
                half2_t hp = u2h(pu);
                float vold = (n15 & 1) ? (float)hp[1] : (float)hp[0];
                vnew = vold + acc2[nt][r];
            }
            float vpart = __shfl_xor(vnew, 1, 64);
            if ((n15 & 1) == 0) {
                unsigned pv = pk2(vnew, vpart);
                int pidx = nt * 8 + (n15 >> 1);
                MU[wid][(4 * q + r) * 33 + pidx] = pv;
                if (node < NN) xh[((size_t)node << 5) + pidx] = pv;
            }
        }
    }

    if (do_zero) {   // re-zero exactly the agg chunks this lane read
        if (nodeB < NN) {
            float4 z4; z4.x = z4.y = z4.z = z4.w = 0.0f;
            float4* ap = (float4*)(agg + ((size_t)nodeB << 6));
            ap[2*q] = z4; ap[2*q + 1] = z4;
            ap[8 + 2*q] = z4; ap[8 + 2*q + 1] = z4;
        }
    }

    if (do_head) {
        __syncthreads();   // MU visibility
        f32x4 acch[4];
#pragma unroll
        for (int mt = 0; mt < 4; ++mt)
            acch[mt] = *(const f32x4*)(ehb1 + mt * 16 + q * 4);
#pragma unroll
        for (int ks = 0; ks < 2; ++ks) {
            U4H8 bfk;
            bfk.u.x = MU[wid][n15 * 33 + ks * 16 + 4 * q + 0];
            bfk.u.y = MU[wid][n15 * 33 + ks * 16 + 4 * q + 1];
            bfk.u.z = MU[wid][n15 * 33 + ks * 16 + 4 * q + 2];
            bfk.u.w = MU[wid][n15 * 33 + ks * 16 + 4 * q + 3];
#pragma unroll
            for (int mt = 0; mt < 4; ++mt) {
                U4H8 af;
                af.u = *(const uint4*)(ehw1t + (size_t)(mt * 16 + n15) * 32 + ks * 16 + q * 4);
                acch[mt] = __builtin_amdgcn_mfma_f32_16x16x32_f16(
                    af.h, bfk.h, acch[mt], 0, 0, 0);
            }
        }
        f32x4 wv[4];
#pragma unroll
        for (int mt = 0; mt < 4; ++mt)
            wv[mt] = *(const f32x4*)(ehw2 + mt * 16 + q * 4);
        float e = 0.0f;
#pragma unroll
        for (int mt = 0; mt < 4; ++mt)
#pragma unroll
            for (int r = 0; r < 4; ++r)
                e = fmaf(silu_f(acch[mt][r]), wv[mt][r], e);
        e += __shfl_xor(e, 16, 64);
        e += __shfl_xor(e, 32, 64);
        if (q == 0) {
            int node = base16 + n15;
            if (node < NN) atomicAdd(&esum[batch[node]], e + ehb2[0]);
        }
        __syncthreads();
        if (tid < NGRAPH) {
            float v = esum[tid];
            if (v != 0.0f) atomicAdd(energy + tid, v);
        }
    }
}

extern "C" void kernel_launch(void* const* d_in, const int* in_sizes, int n_in,
                              void* d_out, int out_size, void* d_ws, size_t ws_size,
                              hipStream_t stream) {
    const int*   z       = (const int*)  d_in[0];
    const float* pos     = (const float*)d_in[1];
    const int*   eidx    = (const int*)  d_in[2];
    const int*   batch   = (const int*)  d_in[3];
    const float* embed   = (const float*)d_in[4];
    const float* msg_w1  = (const float*)d_in[5];
    const float* msg_b1  = (const float*)d_in[6];
    const float* msg_w2  = (const float*)d_in[7];
    const float* msg_b2  = (const float*)d_in[8];
    const float* upd_w1  = (const float*)d_in[9];
    const float* upd_b1  = (const float*)d_in[10];
    const float* upd_w2  = (const float*)d_in[11];
    const float* upd_b2  = (const float*)d_in[12];
    const float* eh_w1   = (const float*)d_in[13];
    const float* eh_b1   = (const float*)d_in[14];
    const float* eh_w2   = (const float*)d_in[15];
    const float* eh_b2   = (const float*)d_in[16];

    const int* erow = eidx;
    const int* ecol = eidx + EE;

    // ws layout (4-byte units); edgeS offset is 8B-aligned
    float*    agg    = (float*)d_ws;                      // NN*64
    unsigned* xh     = (unsigned*)(agg + (size_t)NN * HH);// NN*32
    int*      deg    = (int*)(xh + (size_t)NN * 32);      // NN
    int*      cursor = deg + NN;                          // NN
    int*      bsum   = cursor + NN;                       // 64
    uint2*    edgeS  = (uint2*)(bsum + 64);               // EE uint2 (8B)
    unsigned* w1t    = (unsigned*)(edgeS + EE);           // NL*64*80
    unsigned* w2t    = w1t + NLAYER * 64 * 80;            // NL*64*32
    unsigned* w1tu   = w2t + NLAYER * 64 * 32;            // NL*64*64
    unsigned* w2tu   = w1tu + NLAYER * 64 * 64;           // NL*64*32
    unsigned* ehw1t  = w2tu + NLAYER * 64 * 32;           // 64*32
    float*    energy = (float*)d_out;

    (void)hipMemsetAsync(energy, 0, NGRAPH * sizeof(float), stream);
    (void)hipMemsetAsync(deg, 0, NN * sizeof(int), stream);

    // prep also zeroes agg (blocks 9487..12611): NN*16 float4 = 3125 blocks
    prep_k<<<12612, 256, 0, stream>>>(
        z, embed, xh,
        msg_w1, msg_w2, upd_w1, upd_w2, eh_w1,
        w1t, w2t, w1tu, w2tu, ehw1t,
        ecol, deg, (float4*)agg);

    scan1_k<<<NBLK1, 1024, 0, stream>>>(deg, cursor, bsum);
    scan2_k<<<1, 64, 0, stream>>>(bsum);
    scatter_k<<<(EE + 255) / 256, 256, 0, stream>>>(
        erow, ecol, pos, cursor, bsum, edgeS);

    for (int l = 0; l < NLAYER; ++l) {
        msg_k<<<EE / 256, 256, 0, stream>>>(
            edgeS, xh,
            w1t + (size_t)l * 64 * 80,
            msg_b1 + (size_t)l * HH,
            w2t + (size_t)l * 64 * 32,
            msg_b2 + (size_t)l * HH,
            agg);
        upd_k<<<(NN + 63) / 64, 256, 0, stream>>>(
            xh, agg,
            w1tu + (size_t)l * 64 * 64,
            upd_b1 + (size_t)l * HH,
            w2tu + (size_t)l * 64 * 32,
            upd_b2 + (size_t)l * HH,
            ehw1t, eh_b1, eh_w2, eh_b2, batch, energy,
            (l == 0) ? 1 : 0,            // re-zero agg for next layer
            (l == NLAYER - 1) ? 1 : 0);  // fused head on last layer
    }
}